// Round 1
// baseline (492.100 us; speedup 1.0000x reference)
//
#include <hip/hip_runtime.h>
#include <math.h>

#define BB 4
#define CC 128
#define HH 48
#define WW 48
#define NSP (HH*WW)          // 2304
#define DCC 256
#define BCN (BB*CC*NSP)      // 1179648
#define BNTOT (BB*NSP)       // 9216
#define KS 6                 // attention key-splits (halved partial traffic vs 12)

typedef float f32x4 __attribute__((ext_vector_type(4)));
typedef __bf16 bf16x8 __attribute__((ext_vector_type(8)));
typedef __bf16 bf16x4 __attribute__((ext_vector_type(4)));

__device__ __forceinline__ float sigmf(float v) { return 1.0f / (1.0f + __expf(-v)); }

// ---------------- LDS-tiled transpose -> bf16(B,N,C), fused elementwise ----------------
// MODE 0: plain  2: spike-fn (aux = tau sums, /NSP at use)  3: dual plain+RoPE + ch-stats
// For C==256: channels <128 read from `in` (=x, stride 128), >=128 from `in2` (=feats, stride 256).
template <int C, int MODE>
__global__ __launch_bounds__(256) void trans_kernel(
    const float* __restrict__ in, const float* __restrict__ in2,
    __bf16* __restrict__ out, __bf16* __restrict__ out2,
    const float* __restrict__ aux, float* __restrict__ sums,
    float* __restrict__ sums2) {
  __shared__ float lds[32][33];
  __shared__ float psum[8][32], psum2[8][32];
  int b = blockIdx.z;
  int n0 = blockIdx.x * 32;
  int c0 = blockIdx.y * 32;
  int tid = threadIdx.x;
  int nn = tid & 31, cs = tid >> 5;
#pragma unroll
  for (int j = 0; j < 4; ++j) {
    int cc = c0 + cs * 4 + j;
    float v;
    if (C == 256) {
      v = (cc < 128) ? in[((size_t)b * 128 + cc) * NSP + n0 + nn]
                     : in2[((size_t)b * 256 + cc) * NSP + n0 + nn];
    } else {
      v = in[((size_t)b * C + cc) * NSP + n0 + nn];
    }
    lds[cs * 4 + j][nn] = v;
  }
  __syncthreads();
  int c = tid & 31, ns = tid >> 5;
  float s = 0.f, s2 = 0.f;
#pragma unroll
  for (int j = 0; j < 4; ++j) {
    int n2 = ns * 4 + j;
    float pv = lds[c][n2];
    if (MODE == 0) {
      out[((size_t)b * NSP + n0 + n2) * C + c0 + c] = (__bf16)pv;
    } else if (MODE == 2) {
      float df = pv;
      float sp = sigmf((df - 1.0f) * 5.0f);
      float tv = aux[b * C + c0 + c] * (1.0f / (float)NSP);
      float e = __expf(-1.0f / (tv + 1e-6f));
      float v = sp * (df * e) + (1.0f - sp) * df;
      out[((size_t)b * NSP + n0 + n2) * C + c0 + c] = (__bf16)v;
    } else if (MODE == 3) {
      s += pv;
      s2 += pv * pv;
      out[((size_t)b * NSP + n0 + n2) * C + c0 + c] = (__bf16)pv;
      int gc = c0 + c;
      int i = gc >> 1;
      float re = lds[c & ~1][n2];
      float im = lds[c | 1][n2];
      int n = n0 + n2;
      int h = n / WW, w = n % WW;
      float theta = __expf(-9.2103403719761836f * ((float)i) / 64.0f);
      float pos = (float)(h + w) * theta;
      float cs_ = cosf(pos), sn_ = sinf(pos);
      float vr_ = (gc & 1) ? (re * sn_ + im * cs_) : (re * cs_ - im * sn_);
      out2[((size_t)b * NSP + n0 + n2) * C + c0 + c] = (__bf16)vr_;
    }
  }
  if (MODE == 3) {
    // per-block channel partial sums (BN stats for channels 0..127 == x)
    psum[ns][c] = s;
    psum2[ns][c] = s2;
    __syncthreads();
    if (tid < 32) {
      float S = 0.f, S2 = 0.f;
#pragma unroll
      for (int r2 = 0; r2 < 8; ++r2) {
        S += psum[r2][tid];
        S2 += psum2[r2][tid];
      }
      atomicAdd(&sums[c0 + tid], S);
      atomicAdd(&sums2[c0 + tid], S2);
    }
  }
}

// ---------------- merged prep: weight cvt (12) + conv3x3 pack (4) + accumulator zero ----------------
struct Prep {
  const float* wsrc[12];
  int wlen[12];
  int woff[12];
  const float* psrc[4];
  int pcin[4];
  int poff[4];
  float* zbuf;
  int zlen;
};
__global__ __launch_bounds__(256) void prep_kernel(Prep a, __bf16* __restrict__ wdst,
                                                   __bf16* __restrict__ pdst) {
  int g = blockIdx.y;
  int idx = blockIdx.x * 256 + threadIdx.x;
  if (g < 12) {
    if (idx < a.wlen[g]) wdst[a.woff[g] + idx] = (__bf16)a.wsrc[g][idx];
  } else if (g < 16) {
    int L = g - 12;
    int cin = a.pcin[L];
    if (idx < 9 * 32 * cin) {
      int c = idx % cin;
      int o = (idx / cin) % 32;
      int tap = idx / (cin * 32);
      pdst[a.poff[L] + idx] = (__bf16)a.psrc[L][((size_t)o * cin + c) * 9 + tap];
    }
  } else {
    if (idx < a.zlen) a.zbuf[idx] = 0.f;
  }
}

// ---------------- segmented-epilogue MFMA GEMM ----------------
// OUT: 0 f32 planar, 1 bf16 transposed, 2 bf16 planar, 3 atomic per-channel sum (no store).
// ACT: 0 none, 1 relu, 2 sigmoid, 3 relu^2, 4 fused rwkv epilogue (bias1=u, add0=k, add1=v,
//       out0=knum, out1=rec; r never materialized).
template <int OUT>
__device__ __forceinline__ void gemm_store(void* outp, int b, int n, int Oseg,
                                           int obase, int quad, const float* vr) {
  if (OUT == 0) {
    float* op = (float*)outp;
#pragma unroll
    for (int reg = 0; reg < 4; ++reg)
      op[((size_t)b * Oseg + obase + quad * 4 + reg) * NSP + n] = vr[reg];
  } else if (OUT == 1) {
    __bf16* op = (__bf16*)outp;
    bf16x4 pk;
#pragma unroll
    for (int reg = 0; reg < 4; ++reg) pk[reg] = (__bf16)vr[reg];
    *(bf16x4*)(op + ((size_t)b * NSP + n) * Oseg + obase + quad * 4) = pk;
  } else {
    __bf16* op = (__bf16*)outp;
#pragma unroll
    for (int reg = 0; reg < 4; ++reg)
      op[((size_t)b * Oseg + obase + quad * 4 + reg) * NSP + n] = (__bf16)vr[reg];
  }
}

template <int K, int ACT, int OUT0, int OUT1>
__global__ __launch_bounds__(256) void gemm_mfma_kernel(
    const __bf16* __restrict__ in_t, const __bf16* __restrict__ wb,
    const float* __restrict__ bias0, const float* __restrict__ bias1,
    const float* __restrict__ add0, const float* __restrict__ add1,
    void* __restrict__ out0, void* __restrict__ out1,
    int osplit, int Ototal, float sc0, float sc1) {
  int tid = threadIdx.x;
  int wv = tid >> 6, lane = tid & 63;
  int m15 = lane & 15, quad = lane >> 4;
  int b = blockIdx.y;
  int n0 = blockIdx.x * 16;
  int wpb = blockDim.x >> 6;
  int o0 = (blockIdx.z * wpb + wv) * 32;
  if (o0 >= Ototal) return;
  int n = n0 + m15;
  const __bf16* brow = in_t + ((size_t)b * NSP + n) * K + quad * 8;
  const __bf16* a0p = wb + (size_t)(o0 + m15) * K + quad * 8;
  const __bf16* a1p = wb + (size_t)(o0 + 16 + m15) * K + quad * 8;
  f32x4 of0 = (f32x4){0.f, 0.f, 0.f, 0.f};
  f32x4 of1 = (f32x4){0.f, 0.f, 0.f, 0.f};
#pragma unroll
  for (int kc = 0; kc < K; kc += 32) {
    bf16x8 bfr = *(const bf16x8*)(brow + kc);
    bf16x8 a0 = *(const bf16x8*)(a0p + kc);
    bf16x8 a1 = *(const bf16x8*)(a1p + kc);
    of0 = __builtin_amdgcn_mfma_f32_16x16x32_bf16(a0, bfr, of0, 0, 0, 0);
    of1 = __builtin_amdgcn_mfma_f32_16x16x32_bf16(a1, bfr, of1, 0, 0, 0);
  }
  bool s1 = (o0 >= osplit);
  int Oseg = s1 ? (Ototal - osplit) : osplit;
  int ol0 = o0 - (s1 ? osplit : 0);
  const float* bias = s1 ? bias1 : bias0;
  const float* add = s1 ? add1 : add0;
  void* outp = s1 ? out1 : out0;
  float sc = s1 ? sc1 : sc0;
  if constexpr (ACT == 4) {
    // fused rwkv: rr = sigmoid(x_t·Wr + rb); knum = k*v; rec = rr*((kv+eu*kv)/(k+eu*k))
    float* knum_ = (float*)out0;
    float* rec_ = (float*)out1;
#pragma unroll
    for (int t = 0; t < 2; ++t) {
      f32x4 acc = t ? of1 : of0;
#pragma unroll
      for (int reg = 0; reg < 4; ++reg) {
        int ol = ol0 + t * 16 + quad * 4 + reg;
        float rr = sigmf(acc[reg] + bias0[ol]);
        float eu = __expf(bias1[ol]);  // bias1 = u
        size_t idx = ((size_t)b * 128 + ol) * NSP + n;
        float kk = add0[idx], vv = add1[idx];
        float nv = kk * vv, tt = eu * kk;
        knum_[idx] = nv;
        rec_[idx] = rr * ((nv + tt * vv) / (kk + tt));
      }
    }
  } else {
#pragma unroll
    for (int t = 0; t < 2; ++t) {
      f32x4 acc = t ? of1 : of0;
      float vr[4];
#pragma unroll
      for (int reg = 0; reg < 4; ++reg) {
        int ol = ol0 + t * 16 + quad * 4 + reg;
        float v = acc[reg] + bias[ol];
        if (ACT == 1) v = fmaxf(v, 0.0f);
        else if (ACT == 2) v = sigmf(v);
        else if (ACT == 3) { v = fmaxf(v, 0.0f); v = v * v; }
        v *= sc;
        if (add) v += add[((size_t)b * Oseg + ol) * NSP + n];
        vr[reg] = v;
      }
      if constexpr (OUT0 == 3) {
        // atomic per-channel sum over n (tau fusion): reduce the 16 n-lanes, 1 atomic/quad
#pragma unroll
        for (int reg = 0; reg < 4; ++reg) {
          float sv = vr[reg];
          sv += __shfl_xor(sv, 1);
          sv += __shfl_xor(sv, 2);
          sv += __shfl_xor(sv, 4);
          sv += __shfl_xor(sv, 8);
          if (m15 == 0)
            atomicAdd((float*)out0 + (size_t)b * DCC + ol0 + t * 16 + quad * 4 + reg, sv);
        }
      } else {
        if (!s1)
          gemm_store<OUT0>(outp, b, n, Oseg, ol0 + t * 16, quad, vr);
        else
          gemm_store<OUT1>(outp, b, n, Oseg, ol0 + t * 16, quad, vr);
      }
    }
  }
}

// ---------------- tiled BN+ReLU -> ht (B,N,DCC-stride) bf16; mean/var derived from sums ----------------
// Processes only this call's channel window (incremental across dense layers).
__global__ __launch_bounds__(256) void bnrelu_t_kernel(
    const float* __restrict__ src, size_t bstride, int gcoff,
    const float* __restrict__ sums, const float* __restrict__ sums2,
    const float* __restrict__ g, const float* __restrict__ bb,
    __bf16* __restrict__ ht) {
  __shared__ float lds[32][33];
  int b = blockIdx.z;
  int n0 = blockIdx.x * 32;
  int c0 = blockIdx.y * 32;
  int tid = threadIdx.x;
  int nn = tid & 31, cs = tid >> 5;
#pragma unroll
  for (int j = 0; j < 4; ++j) {
    int cc = c0 + cs * 4 + j;
    lds[cs * 4 + j][nn] = src[(size_t)b * bstride + (size_t)cc * NSP + n0 + nn];
  }
  __syncthreads();
  int c = tid & 31, ns = tid >> 5;
  int gc = gcoff + c0 + c;
  const float inv = 1.0f / (float)(BB * NSP);
  float m = sums[gc] * inv;
  float var = sums2[gc] * inv - m * m;
  float sc_ = rsqrtf(var + 1e-5f) * g[gc];
  float sh_ = bb[gc] - m * sc_;
#pragma unroll
  for (int j = 0; j < 4; ++j) {
    int n2 = ns * 4 + j;
    float v = fmaxf(lds[c][n2] * sc_ + sh_, 0.0f);
    ht[((size_t)b * NSP + n0 + n2) * DCC + gc] = (__bf16)v;
  }
}

// ---------------- conv3x3: 4 waves split tap x K chunks, LDS partial reduce ----------------
// Epilogue optionally accumulates per-output-channel BN stats (atomics) for the next layer.
template <int Cin>
__global__ __launch_bounds__(256) void conv3x3_mfma_kernel(
    const __bf16* __restrict__ ht, const __bf16* __restrict__ wb,
    const float* __restrict__ cb, float* __restrict__ feats, int cout0,
    int do_stats, float* __restrict__ sums, float* __restrict__ sums2) {
  constexpr int KCin = Cin / 32;
  __shared__ float red[4][64][8];
  int tid = threadIdx.x;
  int wv = tid >> 6, lane = tid & 63;
  int m15 = lane & 15, quad = lane >> 4;
  int b = blockIdx.y;
  int n0 = blockIdx.x * 16;
  int n = n0 + m15;
  int h = n / WW, w = n % WW;
  f32x4 of0 = (f32x4){0.f, 0.f, 0.f, 0.f};
  f32x4 of1 = (f32x4){0.f, 0.f, 0.f, 0.f};
  const __bf16* htb = ht + (size_t)b * NSP * DCC;
  const bf16x8 zf = {};
  for (int ci = wv; ci < 9 * KCin; ci += 4) {
    int tap = ci / KCin;
    int kc = (ci % KCin) * 32;
    int dh = tap / 3 - 1, dw = tap % 3 - 1;
    bool valid = ((unsigned)(h + dh) < HH) && ((unsigned)(w + dw) < WW);
    int pa = valid ? (n + dh * WW + dw) : 0;
    bf16x8 bfr = *(const bf16x8*)(htb + (size_t)pa * DCC + kc + quad * 8);
    if (!valid) bfr = zf;
    const __bf16* wt = wb + (size_t)tap * 32 * Cin + kc + quad * 8;
    bf16x8 a0 = *(const bf16x8*)(wt + (size_t)m15 * Cin);
    bf16x8 a1 = *(const bf16x8*)(wt + (size_t)(16 + m15) * Cin);
    of0 = __builtin_amdgcn_mfma_f32_16x16x32_bf16(a0, bfr, of0, 0, 0, 0);
    of1 = __builtin_amdgcn_mfma_f32_16x16x32_bf16(a1, bfr, of1, 0, 0, 0);
  }
  float* myred = red[wv][lane];
#pragma unroll
  for (int reg = 0; reg < 4; ++reg) {
    myred[reg] = of0[reg];
    myred[4 + reg] = of1[reg];
  }
  __syncthreads();
  if (wv == 0) {
#pragma unroll
    for (int reg = 0; reg < 4; ++reg) {
      int o = quad * 4 + reg;
      float v0 = red[0][lane][reg] + red[1][lane][reg] + red[2][lane][reg] +
                 red[3][lane][reg] + cb[o];
      float v1 = red[0][lane][4 + reg] + red[1][lane][4 + reg] + red[2][lane][4 + reg] +
                 red[3][lane][4 + reg] + cb[16 + o];
      feats[((size_t)b * DCC + cout0 + o) * NSP + n] = v0;
      feats[((size_t)b * DCC + cout0 + 16 + o) * NSP + n] = v1;
      if (do_stats) {
        float a0 = v0, q0 = v0 * v0, a1 = v1, q1 = v1 * v1;
#pragma unroll
        for (int mk = 1; mk < 16; mk <<= 1) {
          a0 += __shfl_xor(a0, mk);
          q0 += __shfl_xor(q0, mk);
          a1 += __shfl_xor(a1, mk);
          q1 += __shfl_xor(q1, mk);
        }
        if (m15 == 0) {
          atomicAdd(&sums[cout0 + o], a0);
          atomicAdd(&sums2[cout0 + o], q0);
          atomicAdd(&sums[cout0 + 16 + o], a1);
          atomicAdd(&sums2[cout0 + 16 + o], q1);
        }
      }
    }
  }
}

// ---------------- flash-LDS MFMA attention: 4 waves share K/V tiles via LDS ----------------
template <int CD>
__global__ __launch_bounds__(256) void attn_part_kernel(
    const __bf16* __restrict__ Qt, const __bf16* __restrict__ Kt,
    const __bf16* __restrict__ Vb, __bf16* __restrict__ Op,
    float* __restrict__ lp) {
  constexpr int NC = CD / 16;
  constexpr int KC = CD / 32;
  constexpr int KEYS = NSP / KS;  // 384
  constexpr int KP = CD + 4;
  constexpr int VP = 36;
  __shared__ __bf16 kl[32][KP];
  __shared__ __bf16 vl[CD][VP];
  __shared__ float pt[4][16][36];
  int tid = threadIdx.x;
  int wv = tid >> 6, lane = tid & 63;
  int m15 = lane & 15, quad = lane >> 4;
  int b = blockIdx.y, ks = blockIdx.z;
  int n0 = blockIdx.x * 64 + wv * 16;

  bf16x8 qf[KC];
  const __bf16* qrow = Qt + ((size_t)b * NSP + n0 + m15) * CD + quad * 8;
#pragma unroll
  for (int kc = 0; kc < KC; ++kc) qf[kc] = *(const bf16x8*)(qrow + kc * 32);

  f32x4 of[NC];
#pragma unroll
  for (int i = 0; i < NC; ++i) of[i] = (f32x4){0.f, 0.f, 0.f, 0.f};
  float l0 = 0.f, l1 = 0.f, l2 = 0.f, l3 = 0.f;

  const __bf16* Kb = Kt + (size_t)b * NSP * CD;
  const __bf16* Vbb = Vb + (size_t)b * CD * NSP;
  float(*ptw)[36] = pt[wv];

  for (int m0 = ks * KEYS; m0 < (ks + 1) * KEYS; m0 += 32) {
    __syncthreads();
    for (int i = tid; i < 32 * CD / 8; i += 256) {
      int row = i / (CD / 8);
      int cc8 = (i % (CD / 8)) * 8;
      *(bf16x8*)&kl[row][cc8] = *(const bf16x8*)(Kb + (size_t)(m0 + row) * CD + cc8);
    }
    for (int i = tid; i < CD * 4; i += 256) {
      int ch = i / 4;
      int k8 = (i % 4) * 8;
      *(bf16x8*)&vl[ch][k8] = *(const bf16x8*)(Vbb + (size_t)ch * NSP + m0 + k8);
    }
    __syncthreads();
    f32x4 s[2];
#pragma unroll
    for (int t = 0; t < 2; ++t) {
      f32x4 acc = (f32x4){0.f, 0.f, 0.f, 0.f};
#pragma unroll
      for (int kc = 0; kc < KC; ++kc) {
        bf16x8 kf = *(const bf16x8*)&kl[t * 16 + m15][kc * 32 + quad * 8];
        acc = __builtin_amdgcn_mfma_f32_16x16x32_bf16(qf[kc], kf, acc, 0, 0, 0);
      }
      s[t] = acc;
    }
#pragma unroll
    for (int t = 0; t < 2; ++t) {
      float e0 = __expf(s[t].x), e1 = __expf(s[t].y), e2 = __expf(s[t].z), e3 = __expf(s[t].w);
      l0 += e0; l1 += e1; l2 += e2; l3 += e3;
      ptw[quad * 4 + 0][t * 16 + m15] = e0;
      ptw[quad * 4 + 1][t * 16 + m15] = e1;
      ptw[quad * 4 + 2][t * 16 + m15] = e2;
      ptw[quad * 4 + 3][t * 16 + m15] = e3;
    }
    const float* prow = &ptw[m15][quad * 8];
    f32x4 pa = *(const f32x4*)(prow);
    f32x4 pb = *(const f32x4*)(prow + 4);
    bf16x8 pf;
    pf[0] = (__bf16)pa.x; pf[1] = (__bf16)pa.y; pf[2] = (__bf16)pa.z; pf[3] = (__bf16)pa.w;
    pf[4] = (__bf16)pb.x; pf[5] = (__bf16)pb.y; pf[6] = (__bf16)pb.z; pf[7] = (__bf16)pb.w;
#pragma unroll
    for (int ct = 0; ct < NC; ++ct) {
      bf16x8 vf = *(const bf16x8*)&vl[ct * 16 + m15][quad * 8];
      of[ct] = __builtin_amdgcn_mfma_f32_16x16x32_bf16(pf, vf, of[ct], 0, 0, 0);
    }
  }

#pragma unroll
  for (int off = 1; off < 16; off <<= 1) {
    l0 += __shfl_xor(l0, off);
    l1 += __shfl_xor(l1, off);
    l2 += __shfl_xor(l2, off);
    l3 += __shfl_xor(l3, off);
  }
  float* lpb = lp + (size_t)(ks * BB + b) * NSP + n0;
  if (m15 == 0) {
    lpb[quad * 4 + 0] = l0;
    lpb[quad * 4 + 1] = l1;
    lpb[quad * 4 + 2] = l2;
    lpb[quad * 4 + 3] = l3;
  }
  __bf16* Ob = Op + (size_t)(ks * BB + b) * CD * NSP;
#pragma unroll
  for (int ct = 0; ct < NC; ++ct) {
    bf16x4 pk;
#pragma unroll
    for (int reg = 0; reg < 4; ++reg) pk[reg] = (__bf16)of[ct][reg];
    *(bf16x4*)(Ob + (size_t)(ct * 16 + m15) * NSP + n0 + quad * 4) = pk;
  }
}

// combine partials for CD=32 -> att1_t (B,N,32) bf16 (ltot fused)
__global__ __launch_bounds__(256) void combine32_kernel(const __bf16* __restrict__ Op,
                                                        const float* __restrict__ lp,
                                                        __bf16* __restrict__ att1_t) {
  __shared__ float lds[32][33];
  int b = blockIdx.z;
  int n0 = blockIdx.x * 32;
  int tid = threadIdx.x;
  int nn = tid & 31, cs = tid >> 5;
  float ltot = 0.f;
#pragma unroll
  for (int ks = 0; ks < KS; ++ks) ltot += lp[(size_t)(ks * BB + b) * NSP + n0 + nn];
  float linv = 1.0f / ltot;
#pragma unroll
  for (int j = 0; j < 4; ++j) {
    int cc = cs * 4 + j;
    float s = 0.f;
#pragma unroll
    for (int ks = 0; ks < KS; ++ks)
      s += (float)Op[((size_t)(ks * BB + b) * 32 + cc) * NSP + n0 + nn];
    lds[cc][nn] = s * linv;
  }
  __syncthreads();
  int c = tid & 31, ns = tid >> 5;
#pragma unroll
  for (int j = 0; j < 4; ++j) {
    int n2 = ns * 4 + j;
    att1_t[((size_t)b * NSP + n0 + n2) * 32 + c] = (__bf16)lds[c][n2];
  }
}

// combine partials for CD=128, + x residual -> x1 (f32 planar) AND x1_t (bf16 transposed)
__global__ __launch_bounds__(256) void combine128_kernel(
    const __bf16* __restrict__ Op, const float* __restrict__ lp,
    const float* __restrict__ x, float* __restrict__ x1, __bf16* __restrict__ x1_t) {
  __shared__ float lds[32][33];
  int b = blockIdx.z;
  int n0 = blockIdx.x * 32;
  int c0 = blockIdx.y * 32;
  int tid = threadIdx.x;
  int nn = tid & 31, cs = tid >> 5;
  float ltot = 0.f;
#pragma unroll
  for (int ks = 0; ks < KS; ++ks) ltot += lp[(size_t)(ks * BB + b) * NSP + n0 + nn];
  float linv = 1.0f / ltot;
#pragma unroll
  for (int j = 0; j < 4; ++j) {
    int gc = c0 + cs * 4 + j;
    float s = 0.f;
#pragma unroll
    for (int ks = 0; ks < KS; ++ks)
      s += (float)Op[((size_t)(ks * BB + b) * CC + gc) * NSP + n0 + nn];
    float v = s * linv + x[((size_t)b * CC + gc) * NSP + n0 + nn];
    lds[cs * 4 + j][nn] = v;
    x1[((size_t)b * CC + gc) * NSP + n0 + nn] = v;
  }
  __syncthreads();
  int c = tid & 31, ns = tid >> 5;
#pragma unroll
  for (int j = 0; j < 4; ++j) {
    int n2 = ns * 4 + j;
    x1_t[((size_t)b * NSP + n0 + n2) * CC + c0 + c] = (__bf16)lds[c][n2];
  }
}

// ---------------- host ----------------
extern "C" void kernel_launch(void* const* d_in, const int* in_sizes, int n_in,
                              void* d_out, int out_size, void* d_ws, size_t ws_size,
                              hipStream_t stream) {
  const float* x = (const float*)d_in[0];
  const float* r_w = (const float*)d_in[1];
  const float* r_b = (const float*)d_in[2];
  const float* k_w = (const float*)d_in[3];
  const float* k_b = (const float*)d_in[4];
  const float* v_w = (const float*)d_in[5];
  const float* v_b = (const float*)d_in[6];
  // d_in[7..10]: wc1/wc2 — dead code (multiplied by zeros in reference)
  const float* u = (const float*)d_in[11];
  const float* sn1_w = (const float*)d_in[12];
  const float* sn1_b = (const float*)d_in[13];
  const float* sn2_w = (const float*)d_in[14];
  const float* sn2_b = (const float*)d_in[15];
  const float* lb_w = (const float*)d_in[16];
  const float* lb_b = (const float*)d_in[17];
  const float* ld_w = (const float*)d_in[18];
  const float* ld_b = (const float*)d_in[19];
  const float* ps_w = (const float*)d_in[20];
  const float* ps_b = (const float*)d_in[21];
  const float* pq_w = (const float*)d_in[22];
  const float* pq_b = (const float*)d_in[23];
  const float* fc1_w = (const float*)d_in[24];
  const float* fc1_b = (const float*)d_in[25];
  const float* fc2_w = (const float*)d_in[26];
  const float* fc2_b = (const float*)d_in[27];
  const float* db_g[4] = {(const float*)d_in[28], (const float*)d_in[32],
                          (const float*)d_in[36], (const float*)d_in[40]};
  const float* db_b[4] = {(const float*)d_in[29], (const float*)d_in[33],
                          (const float*)d_in[37], (const float*)d_in[41]};
  const float* db_w[4] = {(const float*)d_in[30], (const float*)d_in[34],
                          (const float*)d_in[38], (const float*)d_in[42]};
  const float* db_cb[4] = {(const float*)d_in[31], (const float*)d_in[35],
                           (const float*)d_in[39], (const float*)d_in[43]};

  float* outp = (float*)d_out;           // out  (B,C,H,W)
  float* knum = outp + BCN;              // new_num = k*v
  float* kden = outp + 2 * (size_t)BCN;  // new_den = k

  float* ws = (float*)d_ws;
  // region map (f32 slots)
  const size_t F_FEATS = 0;         // feats f32 -> Op partials -> h_t bf16
  const size_t F_REC = 4718592;     // rec f32 (1179648)
  const size_t F_V = 5898240;       // v f32 -> ht bf16 -> sf_t bf16 (1179648)
  const size_t F_R = 7077888;       // feats_t bf16 -> V2b bf16 -> x1 f32 (1179648)
  const size_t F_XR = 8257536;      // xrope_t bf16 -> z1_t -> Qt (589824)
  const size_t F_XT = 8847360;      // x_t bf16 -> Bft -> K2t (589824)
  const size_t F_DFB = 9437184;     // Dfb bf16 (147456)
  const size_t F_AT1T = 9584640;    // att1_t bf16 (147456)
  const size_t F_CT = 9732096;      // combined_t bf16 -> x1_t bf16 (589824)
  const size_t F_LP = 10321920;     // lp f32 (KS*B*NSP = 55296)
  const size_t F_STATS = 10432512;  // sums[256] sums2[256] tau[1024]
  const size_t F_WB = 10434048;     // conv1x1 weights bf16
  const size_t F_WB3 = 10567168;    // conv3x3 packed weights bf16
  float* sums = ws + F_STATS;
  float* sums2 = ws + F_STATS + 256;
  float* tau = ws + F_STATS + 512;
  float* lp = ws + F_LP;
  __bf16* wbase = (__bf16*)(ws + F_WB);
  __bf16* wb3 = (__bf16*)(ws + F_WB3);
  const int W_KV = 0;
  const int W_R = 32768;
  const int W_SN1 = 49152;
  const int W_SN2 = 65536;
  const int W_LBLD = 81920;
  const int W_PS = 98304;
  const int W_PQK = 102400;
  const int W_FC1 = 135168;
  const int W_FC2 = 200704;
  const int W3_OFF[4] = {0, 36864, 82944, 138240};

  dim3 blk(256);

  // --- prep: all weight conversions + conv pack + stats/tau zero, ONE launch ---
  Prep pp;
  pp.wsrc[0] = k_w;    pp.wlen[0] = 16384; pp.woff[0] = W_KV;
  pp.wsrc[1] = v_w;    pp.wlen[1] = 16384; pp.woff[1] = W_KV + 16384;
  pp.wsrc[2] = r_w;    pp.wlen[2] = 16384; pp.woff[2] = W_R;
  pp.wsrc[3] = sn1_w;  pp.wlen[3] = 16384; pp.woff[3] = W_SN1;
  pp.wsrc[4] = sn2_w;  pp.wlen[4] = 16384; pp.woff[4] = W_SN2;
  pp.wsrc[5] = lb_w;   pp.wlen[5] = 8192;  pp.woff[5] = W_LBLD;
  pp.wsrc[6] = ld_w;   pp.wlen[6] = 8192;  pp.woff[6] = W_LBLD + 8192;
  pp.wsrc[7] = ps_w;   pp.wlen[7] = 4096;  pp.woff[7] = W_PS;
  pp.wsrc[8] = pq_w;   pp.wlen[8] = 16384; pp.woff[8] = W_PQK;
  pp.wsrc[9] = k_w;    pp.wlen[9] = 16384; pp.woff[9] = W_PQK + 16384;
  pp.wsrc[10] = fc1_w; pp.wlen[10] = 65536; pp.woff[10] = W_FC1;
  pp.wsrc[11] = fc2_w; pp.wlen[11] = 65536; pp.woff[11] = W_FC2;
  for (int i = 0; i < 4; ++i) {
    pp.psrc[i] = db_w[i];
    pp.pcin[i] = 128 + 32 * i;
    pp.poff[i] = W3_OFF[i];
  }
  pp.zbuf = sums;  // sums(256) + sums2(256) + tau(1024)
  pp.zlen = 1536;
  prep_kernel<<<dim3(256, 17), blk, 0, stream>>>(pp, wbase, wb3);

  // --- dual transpose (x_t + xrope_t) + BN stats for channels 0..127 ---
  __bf16* xrope_t = (__bf16*)(ws + F_XR);
  __bf16* x_t = (__bf16*)(ws + F_XT);
  trans_kernel<128, 3><<<dim3(72, 4, 4), blk, 0, stream>>>(x, nullptr, x_t, xrope_t,
                                                           nullptr, sums, sums2);

  // --- recurrent path: fused k|v GEMM, then r GEMM with fused rwkv epilogue ---
  gemm_mfma_kernel<128, 0, 0, 0><<<dim3(144, 4, 2), blk, 0, stream>>>(
      xrope_t, wbase + W_KV, k_b, v_b, nullptr, nullptr, kden, ws + F_V, 128, 256, 1.f, 1.f);
  gemm_mfma_kernel<128, 4, 0, 0><<<dim3(144, 4, 1), blk, 0, stream>>>(
      x_t, wbase + W_R, r_b, u, kden, ws + F_V, knum, ws + F_REC, 128, 128, 1.f, 1.f);

  // --- dense block: incremental bnrelu (new channels only), stats fused into conv epilogue ---
  __bf16* ht = (__bf16*)(ws + F_V);  // v f32 dead after rwkv epilogue
  bnrelu_t_kernel<<<dim3(72, 4, 4), blk, 0, stream>>>(x, (size_t)128 * NSP, 0, sums, sums2,
                                                      db_g[0], db_b[0], ht);
  conv3x3_mfma_kernel<128><<<dim3(144, 4), blk, 0, stream>>>(ht, wb3 + W3_OFF[0], db_cb[0],
                                                             ws + F_FEATS, 128, 1, sums, sums2);
  for (int i = 1; i < 4; ++i) {
    int cin = 128 + 32 * i;
    bnrelu_t_kernel<<<dim3(72, 1, 4), blk, 0, stream>>>(
        ws + F_FEATS + (size_t)(cin - 32) * NSP, (size_t)256 * NSP, cin - 32, sums, sums2,
        db_g[i], db_b[i], ht);
    int dst = (i < 3) ? 1 : 0;
    switch (cin) {
      case 160: conv3x3_mfma_kernel<160><<<dim3(144, 4), blk, 0, stream>>>(ht, wb3 + W3_OFF[i], db_cb[i], ws + F_FEATS, cin, dst, sums, sums2); break;
      case 192: conv3x3_mfma_kernel<192><<<dim3(144, 4), blk, 0, stream>>>(ht, wb3 + W3_OFF[i], db_cb[i], ws + F_FEATS, cin, dst, sums, sums2); break;
      default:  conv3x3_mfma_kernel<224><<<dim3(144, 4), blk, 0, stream>>>(ht, wb3 + W3_OFF[i], db_cb[i], ws + F_FEATS, cin, dst, sums, sums2); break;
    }
  }

  // --- spike path: z2 never materialized (tau fused into sn2 GEMM epilogue) ---
  __bf16* feats_t = (__bf16*)(ws + F_R);
  trans_kernel<256, 0><<<dim3(72, 8, 4), blk, 0, stream>>>(x, ws + F_FEATS, feats_t, nullptr,
                                                           nullptr, nullptr, nullptr);
  __bf16* z1_t = (__bf16*)(ws + F_XR);
  gemm_mfma_kernel<256, 1, 1, 1><<<dim3(144, 4, 1), dim3(128), 0, stream>>>(
      feats_t, wbase + W_SN1, sn1_b, sn1_b, nullptr, nullptr, z1_t, z1_t, 64, 64, 1.f, 1.f);
  gemm_mfma_kernel<64, 2, 3, 3><<<dim3(144, 4, 2), blk, 0, stream>>>(
      z1_t, wbase + W_SN2, sn2_b, sn2_b, nullptr, nullptr, tau, tau, 256, 256, 1.f, 1.f);
  __bf16* sf_t = (__bf16*)(ws + F_V);  // ht dead after last conv
  trans_kernel<256, 2><<<dim3(72, 8, 4), blk, 0, stream>>>(x, ws + F_FEATS, sf_t, nullptr,
                                                           tau, nullptr, nullptr);
  __bf16* Bft = (__bf16*)(ws + F_XT);
  __bf16* Dfb = (__bf16*)(ws + F_DFB);
  gemm_mfma_kernel<256, 0, 1, 2><<<dim3(144, 4, 1), dim3(128), 0, stream>>>(
      sf_t, wbase + W_LBLD, lb_b, ld_b, nullptr, nullptr, Bft, Dfb, 32, 64, 1.f, 1.f);
  __bf16* Opart = (__bf16*)(ws + F_FEATS);  // feats f32 dead from here
  attn_part_kernel<32><<<dim3(36, 4, KS), blk, 0, stream>>>(Bft, Bft, Dfb, Opart, lp);
  __bf16* att1_t = (__bf16*)(ws + F_AT1T);
  combine32_kernel<<<dim3(72, 1, 4), blk, 0, stream>>>(Opart, lp, att1_t);
  __bf16* comb_t = (__bf16*)(ws + F_CT);
  gemm_mfma_kernel<32, 0, 1, 1><<<dim3(144, 4, 1), blk, 0, stream>>>(
      att1_t, wbase + W_PS, ps_b, ps_b, ws + F_REC, ws + F_REC, comb_t, comb_t, 128, 128, 1.f, 1.f);

  // --- final attention: fused Q|K2 GEMM, V2 GEMM, flash-LDS attn ---
  __bf16* Qt = (__bf16*)(ws + F_XR);
  __bf16* K2t = (__bf16*)(ws + F_XT);
  __bf16* V2b = (__bf16*)(ws + F_R);
  gemm_mfma_kernel<128, 0, 1, 1><<<dim3(144, 4, 2), blk, 0, stream>>>(
      comb_t, wbase + W_PQK, pq_b, k_b, nullptr, nullptr, Qt, K2t, 128, 256,
      0.08838834764831845f, 1.f);
  gemm_mfma_kernel<128, 0, 2, 2><<<dim3(144, 4, 1), blk, 0, stream>>>(
      comb_t, wbase + W_KV + 16384, v_b, v_b, nullptr, nullptr, V2b, V2b, 128, 128, 1.f, 1.f);
  attn_part_kernel<128><<<dim3(36, 4, KS), blk, 0, stream>>>(Qt, K2t, V2b, Opart, lp);
  float* x1 = ws + F_R;                 // V2b dead after attn
  __bf16* x1_t = (__bf16*)(ws + F_CT);  // comb_t dead after V2 gemm
  combine128_kernel<<<dim3(72, 4, 4), blk, 0, stream>>>(Opart, lp, x, x1, x1_t);

  // --- FFN tail ---
  __bf16* h_t = (__bf16*)(ws + F_FEATS);  // Op partials dead after combine
  gemm_mfma_kernel<128, 3, 1, 1><<<dim3(144, 4, 4), blk, 0, stream>>>(
      x1_t, wbase + W_FC1, fc1_b, fc1_b, nullptr, nullptr, h_t, h_t, 512, 512, 1.f, 1.f);
  gemm_mfma_kernel<512, 0, 0, 0><<<dim3(144, 4, 1), blk, 0, stream>>>(
      h_t, wbase + W_FC2, fc2_b, fc2_b, x1, x1, outp, outp, 128, 128, 1.f, 1.f);
}

// Round 2
// 431.267 us; speedup vs baseline: 1.1411x; 1.1411x over previous
//
#include <hip/hip_runtime.h>
#include <math.h>

#define BB 4
#define CC 128
#define HH 48
#define WW 48
#define NSP (HH*WW)          // 2304
#define DCC 256
#define BCN (BB*CC*NSP)      // 1179648
#define KS 6                 // attention key-splits

typedef float f32x4 __attribute__((ext_vector_type(4)));
typedef __bf16 bf16x8 __attribute__((ext_vector_type(8)));
typedef __bf16 bf16x4 __attribute__((ext_vector_type(4)));

__device__ __forceinline__ float sigmf(float v) { return 1.0f / (1.0f + __expf(-v)); }

// ---------------- LDS-tiled transpose -> bf16(B,N,C), fused elementwise ----------------
// MODE 2: spike-fn (taupart = per-(b,ch) partial sums, 144 each; reduced in prologue)
// MODE 3: dual plain+RoPE (x_t + xrope_t), no stats
// For C==256: channels <128 read from `in` (=x, stride 128), >=128 from `in2` (=feats, stride 256).
template <int C, int MODE>
__global__ __launch_bounds__(256) void trans_kernel(
    const float* __restrict__ in, const float* __restrict__ in2,
    __bf16* __restrict__ out, __bf16* __restrict__ out2,
    const float* __restrict__ taupart) {
  __shared__ float lds[32][33];
  __shared__ float tauv[32];
  int b = blockIdx.z;
  int n0 = blockIdx.x * 32;
  int c0 = blockIdx.y * 32;
  int tid = threadIdx.x;

  if (MODE == 2) {
    // reduce tau partials for this block's 32 channels (contention-free)
    __shared__ float ttmp[8][32];
    int c = tid & 31, s = tid >> 5;
    const float* tp = taupart + ((size_t)(b * DCC + c0 + c)) * 144 + s * 18;
    float a = 0.f;
#pragma unroll
    for (int j = 0; j < 18; ++j) a += tp[j];
    ttmp[s][c] = a;
    __syncthreads();
    if (tid < 32) {
      float t = 0.f;
#pragma unroll
      for (int s2 = 0; s2 < 8; ++s2) t += ttmp[s2][tid];
      tauv[tid] = t * (1.0f / (float)NSP);
    }
    __syncthreads();
  }

  int nn = tid & 31, cs = tid >> 5;
#pragma unroll
  for (int j = 0; j < 4; ++j) {
    int cc = c0 + cs * 4 + j;
    float v;
    if (C == 256) {
      v = (cc < 128) ? in[((size_t)b * 128 + cc) * NSP + n0 + nn]
                     : in2[((size_t)b * 256 + cc) * NSP + n0 + nn];
    } else {
      v = in[((size_t)b * C + cc) * NSP + n0 + nn];
    }
    lds[cs * 4 + j][nn] = v;
  }
  __syncthreads();
  int c = tid & 31, ns = tid >> 5;
#pragma unroll
  for (int j = 0; j < 4; ++j) {
    int n2 = ns * 4 + j;
    float pv = lds[c][n2];
    if (MODE == 2) {
      float df = pv;
      float sp = sigmf((df - 1.0f) * 5.0f);
      float e = __expf(-1.0f / (tauv[c] + 1e-6f));
      float v = sp * (df * e) + (1.0f - sp) * df;
      out[((size_t)b * NSP + n0 + n2) * C + c0 + c] = (__bf16)v;
    } else if (MODE == 3) {
      out[((size_t)b * NSP + n0 + n2) * C + c0 + c] = (__bf16)pv;
      int gc = c0 + c;
      int i = gc >> 1;
      float re = lds[c & ~1][n2];
      float im = lds[c | 1][n2];
      int n = n0 + n2;
      int h = n / WW, w = n % WW;
      float theta = __expf(-9.2103403719761836f * ((float)i) / 64.0f);
      float pos = (float)(h + w) * theta;
      float cs_ = cosf(pos), sn_ = sinf(pos);
      float vr_ = (gc & 1) ? (re * sn_ + im * cs_) : (re * cs_ - im * sn_);
      out2[((size_t)b * NSP + n0 + n2) * C + c0 + c] = (__bf16)vr_;
    }
  }
}

// ---------------- merged prep: weight cvt (13) + conv3x3 pack (4) + x-channel stats ----------------
struct Prep {
  const float* wsrc[13];
  int wlen[13];
  int woff[13];
  const float* psrc[4];
  int pcin[4];
  int poff[4];
  const float* x;
  float* sums;
  float* sums2;
};
__global__ __launch_bounds__(256) void prep_kernel(Prep a, __bf16* __restrict__ wdst,
                                                   __bf16* __restrict__ pdst) {
  int g = blockIdx.y;
  int idx = blockIdx.x * 256 + threadIdx.x;
  if (g < 13) {
    if (idx < a.wlen[g]) wdst[a.woff[g] + idx] = (__bf16)a.wsrc[g][idx];
  } else if (g < 17) {
    int L = g - 13;
    int cin = a.pcin[L];
    if (idx < 9 * 32 * cin) {
      int c = idx % cin;
      int o = (idx / cin) % 32;
      int tap = idx / (cin * 32);
      pdst[a.poff[L] + idx] = (__bf16)a.psrc[L][((size_t)o * cin + c) * 9 + tap];
    }
  } else {
    // x-channel BN stats: one block per channel (plain stores, no atomics)
    int c = blockIdx.x;
    if (c >= 128) return;
    float s = 0.f, s2 = 0.f;
    for (int i = threadIdx.x; i < BB * NSP; i += 256) {
      int b = i / NSP, n = i % NSP;
      float v = a.x[((size_t)b * 128 + c) * NSP + n];
      s += v;
      s2 += v * v;
    }
    __shared__ float rs[4], rs2[4];
#pragma unroll
    for (int off = 32; off > 0; off >>= 1) {
      s += __shfl_down(s, off);
      s2 += __shfl_down(s2, off);
    }
    int wid = threadIdx.x >> 6;
    if ((threadIdx.x & 63) == 0) { rs[wid] = s; rs2[wid] = s2; }
    __syncthreads();
    if (threadIdx.x == 0) {
      a.sums[c] = rs[0] + rs[1] + rs[2] + rs[3];
      a.sums2[c] = rs2[0] + rs2[1] + rs2[2] + rs2[3];
    }
  }
}

// ---------------- segmented-epilogue MFMA GEMM (up to 3 segments) ----------------
// OUT: 0 f32 planar, 1 bf16 transposed, 2 bf16 planar, 3 per-(b,ch) partial sums (tau).
// ACT: 0 none, 1 relu, 2 sigmoid, 3 relu^2, 4 fused rwkv epilogue.
// SPLITB: B-operand ch<128 from in_t (stride 128), ch>=128 from in_t2 (stride 128).
template <int OUT>
__device__ __forceinline__ void gemm_store(void* outp, int b, int n, int Oseg,
                                           int obase, int quad, const float* vr) {
  if (OUT == 0) {
    float* op = (float*)outp;
#pragma unroll
    for (int reg = 0; reg < 4; ++reg)
      op[((size_t)b * Oseg + obase + quad * 4 + reg) * NSP + n] = vr[reg];
  } else if (OUT == 1) {
    __bf16* op = (__bf16*)outp;
    bf16x4 pk;
#pragma unroll
    for (int reg = 0; reg < 4; ++reg) pk[reg] = (__bf16)vr[reg];
    *(bf16x4*)(op + ((size_t)b * NSP + n) * Oseg + obase + quad * 4) = pk;
  } else {
    __bf16* op = (__bf16*)outp;
#pragma unroll
    for (int reg = 0; reg < 4; ++reg)
      op[((size_t)b * Oseg + obase + quad * 4 + reg) * NSP + n] = (__bf16)vr[reg];
  }
}

template <int K, int ACT, int OUT0, int OUT1, int OUT2, int SPLITB>
__global__ __launch_bounds__(256) void gemm_mfma_kernel(
    const __bf16* __restrict__ in_t, const __bf16* __restrict__ in_t2,
    const __bf16* __restrict__ wb,
    const float* __restrict__ bias0, const float* __restrict__ bias1,
    const float* __restrict__ bias2,
    const float* __restrict__ add0, const float* __restrict__ add1,
    void* __restrict__ out0, void* __restrict__ out1, void* __restrict__ out2,
    int osplit, int osplit2, int Ototal, float sc0, float sc1, float sc2) {
  int tid = threadIdx.x;
  int wv = tid >> 6, lane = tid & 63;
  int m15 = lane & 15, quad = lane >> 4;
  int b = blockIdx.y;
  int n0 = blockIdx.x * 16;
  int wpb = blockDim.x >> 6;
  int o0 = (blockIdx.z * wpb + wv) * 32;
  if (o0 >= Ototal) return;
  int n = n0 + m15;
  const __bf16* brow = in_t + ((size_t)b * NSP + n) * (SPLITB ? 128 : K) + quad * 8;
  const __bf16* brow2 = SPLITB ? (in_t2 + ((size_t)b * NSP + n) * 128 + quad * 8) : nullptr;
  const __bf16* a0p = wb + (size_t)(o0 + m15) * K + quad * 8;
  const __bf16* a1p = wb + (size_t)(o0 + 16 + m15) * K + quad * 8;
  f32x4 of0 = (f32x4){0.f, 0.f, 0.f, 0.f};
  f32x4 of1 = (f32x4){0.f, 0.f, 0.f, 0.f};
#pragma unroll
  for (int kc = 0; kc < K; kc += 32) {
    bf16x8 bfr;
    if constexpr (SPLITB) {
      bfr = (kc < 128) ? *(const bf16x8*)(brow + kc) : *(const bf16x8*)(brow2 + (kc - 128));
    } else {
      bfr = *(const bf16x8*)(brow + kc);
    }
    bf16x8 a0 = *(const bf16x8*)(a0p + kc);
    bf16x8 a1 = *(const bf16x8*)(a1p + kc);
    of0 = __builtin_amdgcn_mfma_f32_16x16x32_bf16(a0, bfr, of0, 0, 0, 0);
    of1 = __builtin_amdgcn_mfma_f32_16x16x32_bf16(a1, bfr, of1, 0, 0, 0);
  }
  int seg = (o0 >= osplit2) ? 2 : (o0 >= osplit) ? 1 : 0;
  int segb = (seg == 2) ? osplit2 : (seg == 1) ? osplit : 0;
  int sege = (seg == 2) ? Ototal : (seg == 1) ? osplit2 : osplit;
  int Oseg = sege - segb;
  int ol0 = o0 - segb;
  const float* bias = (seg == 2) ? bias2 : (seg == 1) ? bias1 : bias0;
  const float* add = (seg == 2) ? nullptr : (seg == 1) ? add1 : add0;
  void* outp = (seg == 2) ? out2 : (seg == 1) ? out1 : out0;
  float sc = (seg == 2) ? sc2 : (seg == 1) ? sc1 : sc0;
  if constexpr (ACT == 4) {
    // fused rwkv: rr = sigmoid(x_t·Wr + rb); knum = k*v; rec = rr*((kv+eu*kv)/(k+eu*k))
    float* knum_ = (float*)out0;
    float* rec_ = (float*)out1;
#pragma unroll
    for (int t = 0; t < 2; ++t) {
      f32x4 acc = t ? of1 : of0;
#pragma unroll
      for (int reg = 0; reg < 4; ++reg) {
        int ol = ol0 + t * 16 + quad * 4 + reg;
        float rr = sigmf(acc[reg] + bias0[ol]);
        float eu = __expf(bias1[ol]);  // bias1 = u
        size_t idx = ((size_t)b * 128 + ol) * NSP + n;
        float kk = add0[idx], vv = add1[idx];
        float nv = kk * vv, tt = eu * kk;
        knum_[idx] = nv;
        rec_[idx] = rr * ((nv + tt * vv) / (kk + tt));
      }
    }
  } else {
#pragma unroll
    for (int t = 0; t < 2; ++t) {
      f32x4 acc = t ? of1 : of0;
      float vr[4];
#pragma unroll
      for (int reg = 0; reg < 4; ++reg) {
        int ol = ol0 + t * 16 + quad * 4 + reg;
        float v = acc[reg] + bias[ol];
        if (ACT == 1) v = fmaxf(v, 0.0f);
        else if (ACT == 2) v = sigmf(v);
        else if (ACT == 3) { v = fmaxf(v, 0.0f); v = v * v; }
        v *= sc;
        if (add) v += add[((size_t)b * Oseg + ol) * NSP + n];
        vr[reg] = v;
      }
      if constexpr (OUT0 == 3) {
        // per-(b,ch) partial row-sum over this block's 16 n (contention-free store)
#pragma unroll
        for (int reg = 0; reg < 4; ++reg) {
          float sv = vr[reg];
          sv += __shfl_xor(sv, 1);
          sv += __shfl_xor(sv, 2);
          sv += __shfl_xor(sv, 4);
          sv += __shfl_xor(sv, 8);
          if (m15 == 0)
            ((float*)out0)[((size_t)(b * DCC + ol0 + t * 16 + quad * 4 + reg)) * 144 +
                           blockIdx.x] = sv;
        }
      } else {
        if (seg == 0) gemm_store<OUT0>(outp, b, n, Oseg, ol0 + t * 16, quad, vr);
        else if (seg == 1) gemm_store<OUT1>(outp, b, n, Oseg, ol0 + t * 16, quad, vr);
        else gemm_store<OUT2>(outp, b, n, Oseg, ol0 + t * 16, quad, vr);
      }
    }
  }
}

// ---------------- tiled BN+ReLU -> ht (B,N,DCC-stride) bf16 ----------------
// Stats: from global sums (cpart==null) or reduced from conv per-block partials (64 x 576).
__global__ __launch_bounds__(256) void bnrelu_t_kernel(
    const float* __restrict__ src, size_t bstride, int gcoff,
    const float* __restrict__ sums, const float* __restrict__ sums2,
    const float* __restrict__ cpart,
    const float* __restrict__ g, const float* __restrict__ bb,
    __bf16* __restrict__ ht) {
  __shared__ float lds[32][33];
  __shared__ float fst[64];
  int b = blockIdx.z;
  int n0 = blockIdx.x * 32;
  int c0 = blockIdx.y * 32;
  int tid = threadIdx.x;

  if (cpart) {
    __shared__ float tmp[4][64];
    int r = tid & 63, sl = tid >> 6;
    const float* cp = cpart + (size_t)r * 576 + sl * 144;
    float a = 0.f;
#pragma unroll 4
    for (int j = 0; j < 144; ++j) a += cp[j];
    tmp[sl][r] = a;
    __syncthreads();
    if (tid < 64) fst[tid] = tmp[0][tid] + tmp[1][tid] + tmp[2][tid] + tmp[3][tid];
    __syncthreads();
  }

  int nn = tid & 31, cs = tid >> 5;
#pragma unroll
  for (int j = 0; j < 4; ++j) {
    int cc = c0 + cs * 4 + j;
    lds[cs * 4 + j][nn] = src[(size_t)b * bstride + (size_t)cc * NSP + n0 + nn];
  }
  __syncthreads();
  int c = tid & 31, ns = tid >> 5;
  int gc = gcoff + c0 + c;
  const float inv = 1.0f / (float)(BB * NSP);
  float S = cpart ? fst[c] : sums[gc];
  float S2 = cpart ? fst[32 + c] : sums2[gc];
  float m = S * inv;
  float var = S2 * inv - m * m;
  float sc_ = rsqrtf(var + 1e-5f) * g[gc];
  float sh_ = bb[gc] - m * sc_;
#pragma unroll
  for (int j = 0; j < 4; ++j) {
    int n2 = ns * 4 + j;
    float v = fmaxf(lds[c][n2] * sc_ + sh_, 0.0f);
    ht[((size_t)b * NSP + n0 + n2) * DCC + gc] = (__bf16)v;
  }
}

// ---------------- conv3x3: 4 waves split tap x K chunks, LDS partial reduce ----------------
// Epilogue: planar f32 feats + transposed bf16 dense_t (+ optional per-block stat partials).
template <int Cin>
__global__ __launch_bounds__(256) void conv3x3_mfma_kernel(
    const __bf16* __restrict__ ht, const __bf16* __restrict__ wb,
    const float* __restrict__ cb, float* __restrict__ feats, int cout0,
    __bf16* __restrict__ dense_t, float* __restrict__ cpart) {
  constexpr int KCin = Cin / 32;
  __shared__ float red[4][64][8];
  int tid = threadIdx.x;
  int wv = tid >> 6, lane = tid & 63;
  int m15 = lane & 15, quad = lane >> 4;
  int b = blockIdx.y;
  int n0 = blockIdx.x * 16;
  int n = n0 + m15;
  int h = n / WW, w = n % WW;
  f32x4 of0 = (f32x4){0.f, 0.f, 0.f, 0.f};
  f32x4 of1 = (f32x4){0.f, 0.f, 0.f, 0.f};
  const __bf16* htb = ht + (size_t)b * NSP * DCC;
  const bf16x8 zf = {};
  for (int ci = wv; ci < 9 * KCin; ci += 4) {
    int tap = ci / KCin;
    int kc = (ci % KCin) * 32;
    int dh = tap / 3 - 1, dw = tap % 3 - 1;
    bool valid = ((unsigned)(h + dh) < HH) && ((unsigned)(w + dw) < WW);
    int pa = valid ? (n + dh * WW + dw) : 0;
    bf16x8 bfr = *(const bf16x8*)(htb + (size_t)pa * DCC + kc + quad * 8);
    if (!valid) bfr = zf;
    const __bf16* wt = wb + (size_t)tap * 32 * Cin + kc + quad * 8;
    bf16x8 a0 = *(const bf16x8*)(wt + (size_t)m15 * Cin);
    bf16x8 a1 = *(const bf16x8*)(wt + (size_t)(16 + m15) * Cin);
    of0 = __builtin_amdgcn_mfma_f32_16x16x32_bf16(a0, bfr, of0, 0, 0, 0);
    of1 = __builtin_amdgcn_mfma_f32_16x16x32_bf16(a1, bfr, of1, 0, 0, 0);
  }
  float* myred = red[wv][lane];
#pragma unroll
  for (int reg = 0; reg < 4; ++reg) {
    myred[reg] = of0[reg];
    myred[4 + reg] = of1[reg];
  }
  __syncthreads();
  if (wv == 0) {
    int dloc = cout0 - 128;
    __bf16* dt = dense_t + ((size_t)b * NSP + n) * 128 + dloc;
#pragma unroll
    for (int reg = 0; reg < 4; ++reg) {
      int o = quad * 4 + reg;
      float v0 = red[0][lane][reg] + red[1][lane][reg] + red[2][lane][reg] +
                 red[3][lane][reg] + cb[o];
      float v1 = red[0][lane][4 + reg] + red[1][lane][4 + reg] + red[2][lane][4 + reg] +
                 red[3][lane][4 + reg] + cb[16 + o];
      feats[((size_t)b * DCC + cout0 + o) * NSP + n] = v0;
      feats[((size_t)b * DCC + cout0 + 16 + o) * NSP + n] = v1;
      dt[o] = (__bf16)v0;
      dt[16 + o] = (__bf16)v1;
      if (cpart) {
        float a0 = v0, q0 = v0 * v0, a1 = v1, q1 = v1 * v1;
#pragma unroll
        for (int mk = 1; mk < 16; mk <<= 1) {
          a0 += __shfl_xor(a0, mk);
          q0 += __shfl_xor(q0, mk);
          a1 += __shfl_xor(a1, mk);
          q1 += __shfl_xor(q1, mk);
        }
        if (m15 == 0) {
          int pidx = blockIdx.y * 144 + blockIdx.x;
          cpart[(size_t)o * 576 + pidx] = a0;
          cpart[(size_t)(32 + o) * 576 + pidx] = q0;
          cpart[(size_t)(16 + o) * 576 + pidx] = a1;
          cpart[(size_t)(48 + o) * 576 + pidx] = q1;
        }
      }
    }
  }
}

// ---------------- flash-LDS MFMA attention: 4 waves share K/V tiles via LDS ----------------
template <int CD>
__global__ __launch_bounds__(256) void attn_part_kernel(
    const __bf16* __restrict__ Qt, const __bf16* __restrict__ Kt,
    const __bf16* __restrict__ Vb, __bf16* __restrict__ Op,
    float* __restrict__ lp) {
  constexpr int NC = CD / 16;
  constexpr int KC = CD / 32;
  constexpr int KEYS = NSP / KS;  // 384
  constexpr int KP = CD + 4;
  constexpr int VP = 36;
  __shared__ __bf16 kl[32][KP];
  __shared__ __bf16 vl[CD][VP];
  __shared__ float pt[4][16][36];
  int tid = threadIdx.x;
  int wv = tid >> 6, lane = tid & 63;
  int m15 = lane & 15, quad = lane >> 4;
  int b = blockIdx.y, ks = blockIdx.z;
  int n0 = blockIdx.x * 64 + wv * 16;

  bf16x8 qf[KC];
  const __bf16* qrow = Qt + ((size_t)b * NSP + n0 + m15) * CD + quad * 8;
#pragma unroll
  for (int kc = 0; kc < KC; ++kc) qf[kc] = *(const bf16x8*)(qrow + kc * 32);

  f32x4 of[NC];
#pragma unroll
  for (int i = 0; i < NC; ++i) of[i] = (f32x4){0.f, 0.f, 0.f, 0.f};
  float l0 = 0.f, l1 = 0.f, l2 = 0.f, l3 = 0.f;

  const __bf16* Kb = Kt + (size_t)b * NSP * CD;
  const __bf16* Vbb = Vb + (size_t)b * CD * NSP;
  float(*ptw)[36] = pt[wv];

  for (int m0 = ks * KEYS; m0 < (ks + 1) * KEYS; m0 += 32) {
    __syncthreads();
    for (int i = tid; i < 32 * CD / 8; i += 256) {
      int row = i / (CD / 8);
      int cc8 = (i % (CD / 8)) * 8;
      *(bf16x8*)&kl[row][cc8] = *(const bf16x8*)(Kb + (size_t)(m0 + row) * CD + cc8);
    }
    for (int i = tid; i < CD * 4; i += 256) {
      int ch = i / 4;
      int k8 = (i % 4) * 8;
      *(bf16x8*)&vl[ch][k8] = *(const bf16x8*)(Vbb + (size_t)ch * NSP + m0 + k8);
    }
    __syncthreads();
    f32x4 s[2];
#pragma unroll
    for (int t = 0; t < 2; ++t) {
      f32x4 acc = (f32x4){0.f, 0.f, 0.f, 0.f};
#pragma unroll
      for (int kc = 0; kc < KC; ++kc) {
        bf16x8 kf = *(const bf16x8*)&kl[t * 16 + m15][kc * 32 + quad * 8];
        acc = __builtin_amdgcn_mfma_f32_16x16x32_bf16(qf[kc], kf, acc, 0, 0, 0);
      }
      s[t] = acc;
    }
#pragma unroll
    for (int t = 0; t < 2; ++t) {
      float e0 = __expf(s[t].x), e1 = __expf(s[t].y), e2 = __expf(s[t].z), e3 = __expf(s[t].w);
      l0 += e0; l1 += e1; l2 += e2; l3 += e3;
      ptw[quad * 4 + 0][t * 16 + m15] = e0;
      ptw[quad * 4 + 1][t * 16 + m15] = e1;
      ptw[quad * 4 + 2][t * 16 + m15] = e2;
      ptw[quad * 4 + 3][t * 16 + m15] = e3;
    }
    const float* prow = &ptw[m15][quad * 8];
    f32x4 pa = *(const f32x4*)(prow);
    f32x4 pb = *(const f32x4*)(prow + 4);
    bf16x8 pf;
    pf[0] = (__bf16)pa.x; pf[1] = (__bf16)pa.y; pf[2] = (__bf16)pa.z; pf[3] = (__bf16)pa.w;
    pf[4] = (__bf16)pb.x; pf[5] = (__bf16)pb.y; pf[6] = (__bf16)pb.z; pf[7] = (__bf16)pb.w;
#pragma unroll
    for (int ct = 0; ct < NC; ++ct) {
      bf16x8 vf = *(const bf16x8*)&vl[ct * 16 + m15][quad * 8];
      of[ct] = __builtin_amdgcn_mfma_f32_16x16x32_bf16(pf, vf, of[ct], 0, 0, 0);
    }
  }

#pragma unroll
  for (int off = 1; off < 16; off <<= 1) {
    l0 += __shfl_xor(l0, off);
    l1 += __shfl_xor(l1, off);
    l2 += __shfl_xor(l2, off);
    l3 += __shfl_xor(l3, off);
  }
  float* lpb = lp + (size_t)(ks * BB + b) * NSP + n0;
  if (m15 == 0) {
    lpb[quad * 4 + 0] = l0;
    lpb[quad * 4 + 1] = l1;
    lpb[quad * 4 + 2] = l2;
    lpb[quad * 4 + 3] = l3;
  }
  __bf16* Ob = Op + (size_t)(ks * BB + b) * CD * NSP;
#pragma unroll
  for (int ct = 0; ct < NC; ++ct) {
    bf16x4 pk;
#pragma unroll
    for (int reg = 0; reg < 4; ++reg) pk[reg] = (__bf16)of[ct][reg];
    *(bf16x4*)(Ob + (size_t)(ct * 16 + m15) * NSP + n0 + quad * 4) = pk;
  }
}

// combine partials for CD=32 -> att1_t (B,N,32) bf16
__global__ __launch_bounds__(256) void combine32_kernel(const __bf16* __restrict__ Op,
                                                        const float* __restrict__ lp,
                                                        __bf16* __restrict__ att1_t) {
  __shared__ float lds[32][33];
  int b = blockIdx.z;
  int n0 = blockIdx.x * 32;
  int tid = threadIdx.x;
  int nn = tid & 31, cs = tid >> 5;
  float ltot = 0.f;
#pragma unroll
  for (int ks = 0; ks < KS; ++ks) ltot += lp[(size_t)(ks * BB + b) * NSP + n0 + nn];
  float linv = 1.0f / ltot;
#pragma unroll
  for (int j = 0; j < 4; ++j) {
    int cc = cs * 4 + j;
    float s = 0.f;
#pragma unroll
    for (int ks = 0; ks < KS; ++ks)
      s += (float)Op[((size_t)(ks * BB + b) * 32 + cc) * NSP + n0 + nn];
    lds[cc][nn] = s * linv;
  }
  __syncthreads();
  int c = tid & 31, ns = tid >> 5;
#pragma unroll
  for (int j = 0; j < 4; ++j) {
    int n2 = ns * 4 + j;
    att1_t[((size_t)b * NSP + n0 + n2) * 32 + c] = (__bf16)lds[c][n2];
  }
}

// combine partials for CD=128, + x residual -> x1 (f32 planar) AND x1_t (bf16 transposed)
__global__ __launch_bounds__(256) void combine128_kernel(
    const __bf16* __restrict__ Op, const float* __restrict__ lp,
    const float* __restrict__ x, float* __restrict__ x1, __bf16* __restrict__ x1_t) {
  __shared__ float lds[32][33];
  int b = blockIdx.z;
  int n0 = blockIdx.x * 32;
  int c0 = blockIdx.y * 32;
  int tid = threadIdx.x;
  int nn = tid & 31, cs = tid >> 5;
  float ltot = 0.f;
#pragma unroll
  for (int ks = 0; ks < KS; ++ks) ltot += lp[(size_t)(ks * BB + b) * NSP + n0 + nn];
  float linv = 1.0f / ltot;
#pragma unroll
  for (int j = 0; j < 4; ++j) {
    int gc = c0 + cs * 4 + j;
    float s = 0.f;
#pragma unroll
    for (int ks = 0; ks < KS; ++ks)
      s += (float)Op[((size_t)(ks * BB + b) * CC + gc) * NSP + n0 + nn];
    float v = s * linv + x[((size_t)b * CC + gc) * NSP + n0 + nn];
    lds[cs * 4 + j][nn] = v;
    x1[((size_t)b * CC + gc) * NSP + n0 + nn] = v;
  }
  __syncthreads();
  int c = tid & 31, ns = tid >> 5;
#pragma unroll
  for (int j = 0; j < 4; ++j) {
    int n2 = ns * 4 + j;
    x1_t[((size_t)b * NSP + n0 + n2) * CC + c0 + c] = (__bf16)lds[c][n2];
  }
}

// ---------------- host ----------------
extern "C" void kernel_launch(void* const* d_in, const int* in_sizes, int n_in,
                              void* d_out, int out_size, void* d_ws, size_t ws_size,
                              hipStream_t stream) {
  const float* x = (const float*)d_in[0];
  const float* r_w = (const float*)d_in[1];
  const float* r_b = (const float*)d_in[2];
  const float* k_w = (const float*)d_in[3];
  const float* k_b = (const float*)d_in[4];
  const float* v_w = (const float*)d_in[5];
  const float* v_b = (const float*)d_in[6];
  // d_in[7..10]: wc1/wc2 — dead code (multiplied by zeros in reference)
  const float* u = (const float*)d_in[11];
  const float* sn1_w = (const float*)d_in[12];
  const float* sn1_b = (const float*)d_in[13];
  const float* sn2_w = (const float*)d_in[14];
  const float* sn2_b = (const float*)d_in[15];
  const float* lb_w = (const float*)d_in[16];
  const float* lb_b = (const float*)d_in[17];
  const float* ld_w = (const float*)d_in[18];
  const float* ld_b = (const float*)d_in[19];
  const float* ps_w = (const float*)d_in[20];
  const float* ps_b = (const float*)d_in[21];
  const float* pq_w = (const float*)d_in[22];
  const float* pq_b = (const float*)d_in[23];
  const float* fc1_w = (const float*)d_in[24];
  const float* fc1_b = (const float*)d_in[25];
  const float* fc2_w = (const float*)d_in[26];
  const float* fc2_b = (const float*)d_in[27];
  const float* db_g[4] = {(const float*)d_in[28], (const float*)d_in[32],
                          (const float*)d_in[36], (const float*)d_in[40]};
  const float* db_b[4] = {(const float*)d_in[29], (const float*)d_in[33],
                          (const float*)d_in[37], (const float*)d_in[41]};
  const float* db_w[4] = {(const float*)d_in[30], (const float*)d_in[34],
                          (const float*)d_in[38], (const float*)d_in[42]};
  const float* db_cb[4] = {(const float*)d_in[31], (const float*)d_in[35],
                           (const float*)d_in[39], (const float*)d_in[43]};

  float* outp = (float*)d_out;           // out  (B,C,H,W)
  float* knum = outp + BCN;              // new_num = k*v
  float* kden = outp + 2 * (size_t)BCN;  // new_den = k

  float* ws = (float*)d_ws;
  // region map (f32 slots)
  const size_t F_FEATS = 0;         // feats f32 -> Op partials -> h_t bf16
  const size_t F_REC = 4718592;     // rec f32 (1179648)
  const size_t F_V = 5898240;       // v f32 -> ht bf16 -> sf_t bf16 -> V2b bf16
  const size_t F_R = 7077888;       // dense_t bf16 (589824) -> x1 f32 (1179648)
  const size_t F_XR = 8257536;      // xrope_t bf16 -> z1_t -> Qt (589824)
  const size_t F_XT = 8847360;      // x_t bf16 -> Bft -> K2t (589824)
  const size_t F_DFB = 9437184;     // Dfb bf16 (147456)
  const size_t F_AT1T = 9584640;    // att1_t bf16 (147456)
  const size_t F_CT = 9732096;      // combined_t bf16 -> x1_t bf16 (589824)
  const size_t F_LP = 10321920;     // lp f32 (KS*B*NSP = 55296)
  const size_t F_WB = 10434048;     // conv1x1 weights bf16 (282624 bf16 = 141312 slots)
  const size_t F_WB3 = 10575360;    // conv3x3 packed weights bf16 (202752 bf16 = 101376 slots)
  const size_t F_STATS = 10676736;  // sums[256] sums2[256]
  const size_t F_CPART = 10677248;  // conv stat partials (64 x 576 = 36864)
  const size_t F_TAUP = 10714112;   // tau partials (1024 x 144 = 147456)
  float* sums = ws + F_STATS;
  float* sums2 = ws + F_STATS + 256;
  float* cpart = ws + F_CPART;
  float* taupart = ws + F_TAUP;
  float* lp = ws + F_LP;
  __bf16* wbase = (__bf16*)(ws + F_WB);
  __bf16* wb3 = (__bf16*)(ws + F_WB3);
  const int W_KV = 0;        // k(16384) | v(16384)
  const int W_R = 32768;     // 16384
  const int W_SN1 = 49152;   // 16384
  const int W_SN2 = 65536;   // 16384
  const int W_LBLD = 81920;  // lb(8192) | ld(8192)
  const int W_PS = 98304;    // 4096
  const int W_PQK = 102400;  // pq(16384) | k(16384) | v(16384)
  const int W_FC1 = 151552;  // 65536
  const int W_FC2 = 217088;  // 65536
  const int W3_OFF[4] = {0, 36864, 82944, 138240};

  dim3 blk(256);

  // --- prep: weight conversions + conv pack + x-channel stats, ONE launch ---
  Prep pp;
  pp.wsrc[0] = k_w;    pp.wlen[0] = 16384; pp.woff[0] = W_KV;
  pp.wsrc[1] = v_w;    pp.wlen[1] = 16384; pp.woff[1] = W_KV + 16384;
  pp.wsrc[2] = r_w;    pp.wlen[2] = 16384; pp.woff[2] = W_R;
  pp.wsrc[3] = sn1_w;  pp.wlen[3] = 16384; pp.woff[3] = W_SN1;
  pp.wsrc[4] = sn2_w;  pp.wlen[4] = 16384; pp.woff[4] = W_SN2;
  pp.wsrc[5] = lb_w;   pp.wlen[5] = 8192;  pp.woff[5] = W_LBLD;
  pp.wsrc[6] = ld_w;   pp.wlen[6] = 8192;  pp.woff[6] = W_LBLD + 8192;
  pp.wsrc[7] = ps_w;   pp.wlen[7] = 4096;  pp.woff[7] = W_PS;
  pp.wsrc[8] = pq_w;   pp.wlen[8] = 16384; pp.woff[8] = W_PQK;
  pp.wsrc[9] = k_w;    pp.wlen[9] = 16384; pp.woff[9] = W_PQK + 16384;
  pp.wsrc[10] = v_w;   pp.wlen[10] = 16384; pp.woff[10] = W_PQK + 32768;
  pp.wsrc[11] = fc1_w; pp.wlen[11] = 65536; pp.woff[11] = W_FC1;
  pp.wsrc[12] = fc2_w; pp.wlen[12] = 65536; pp.woff[12] = W_FC2;
  for (int i = 0; i < 4; ++i) {
    pp.psrc[i] = db_w[i];
    pp.pcin[i] = 128 + 32 * i;
    pp.poff[i] = W3_OFF[i];
  }
  pp.x = x;
  pp.sums = sums;
  pp.sums2 = sums2;
  prep_kernel<<<dim3(256, 18), blk, 0, stream>>>(pp, wbase, wb3);

  // --- dual transpose (x_t + xrope_t) ---
  __bf16* xrope_t = (__bf16*)(ws + F_XR);
  __bf16* x_t = (__bf16*)(ws + F_XT);
  trans_kernel<128, 3><<<dim3(72, 4, 4), blk, 0, stream>>>(x, nullptr, x_t, xrope_t, nullptr);

  // --- recurrent path: fused k|v GEMM, then r GEMM with fused rwkv epilogue ---
  gemm_mfma_kernel<128, 0, 0, 0, 0, 0><<<dim3(144, 4, 2), blk, 0, stream>>>(
      xrope_t, nullptr, wbase + W_KV, k_b, v_b, nullptr, nullptr, nullptr,
      kden, ws + F_V, nullptr, 128, 256, 256, 1.f, 1.f, 1.f);
  gemm_mfma_kernel<128, 4, 0, 0, 0, 0><<<dim3(144, 4, 1), blk, 0, stream>>>(
      x_t, nullptr, wbase + W_R, r_b, u, nullptr, kden, ws + F_V,
      knum, ws + F_REC, nullptr, 128, 128, 128, 1.f, 1.f, 1.f);

  // --- dense block: incremental bnrelu, stats via per-block partials ---
  __bf16* ht = (__bf16*)(ws + F_V);  // v f32 dead after rwkv epilogue
  __bf16* dense_t = (__bf16*)(ws + F_R);
  bnrelu_t_kernel<<<dim3(72, 4, 4), blk, 0, stream>>>(x, (size_t)128 * NSP, 0, sums, sums2,
                                                      nullptr, db_g[0], db_b[0], ht);
  conv3x3_mfma_kernel<128><<<dim3(144, 4), blk, 0, stream>>>(
      ht, wb3 + W3_OFF[0], db_cb[0], ws + F_FEATS, 128, dense_t, cpart);
  for (int i = 1; i < 4; ++i) {
    int cin = 128 + 32 * i;
    bnrelu_t_kernel<<<dim3(72, 1, 4), blk, 0, stream>>>(
        ws + F_FEATS + (size_t)(cin - 32) * NSP, (size_t)256 * NSP, cin - 32,
        nullptr, nullptr, cpart, db_g[i], db_b[i], ht);
    float* cp = (i < 3) ? cpart : nullptr;
    switch (cin) {
      case 160: conv3x3_mfma_kernel<160><<<dim3(144, 4), blk, 0, stream>>>(ht, wb3 + W3_OFF[i], db_cb[i], ws + F_FEATS, cin, dense_t, cp); break;
      case 192: conv3x3_mfma_kernel<192><<<dim3(144, 4), blk, 0, stream>>>(ht, wb3 + W3_OFF[i], db_cb[i], ws + F_FEATS, cin, dense_t, cp); break;
      default:  conv3x3_mfma_kernel<224><<<dim3(144, 4), blk, 0, stream>>>(ht, wb3 + W3_OFF[i], db_cb[i], ws + F_FEATS, cin, dense_t, cp); break;
    }
  }

  // --- spike path: sn1 reads split x_t|dense_t (feats_t eliminated); tau via partials ---
  __bf16* z1_t = (__bf16*)(ws + F_XR);
  gemm_mfma_kernel<256, 1, 1, 1, 0, 1><<<dim3(144, 4, 1), dim3(128), 0, stream>>>(
      x_t, dense_t, wbase + W_SN1, sn1_b, sn1_b, nullptr, nullptr, nullptr,
      z1_t, z1_t, nullptr, 64, 64, 64, 1.f, 1.f, 1.f);
  gemm_mfma_kernel<64, 2, 3, 3, 0, 0><<<dim3(144, 4, 2), blk, 0, stream>>>(
      z1_t, nullptr, wbase + W_SN2, sn2_b, sn2_b, nullptr, nullptr, nullptr,
      taupart, taupart, nullptr, 256, 256, 256, 1.f, 1.f, 1.f);
  __bf16* sf_t = (__bf16*)(ws + F_V);  // ht dead after last conv
  trans_kernel<256, 2><<<dim3(72, 8, 4), blk, 0, stream>>>(x, ws + F_FEATS, sf_t, nullptr,
                                                           taupart);
  __bf16* Bft = (__bf16*)(ws + F_XT);
  __bf16* Dfb = (__bf16*)(ws + F_DFB);
  gemm_mfma_kernel<256, 0, 1, 2, 0, 0><<<dim3(144, 4, 1), dim3(128), 0, stream>>>(
      sf_t, nullptr, wbase + W_LBLD, lb_b, ld_b, nullptr, nullptr, nullptr,
      Bft, Dfb, nullptr, 32, 64, 64, 1.f, 1.f, 1.f);
  __bf16* Opart = (__bf16*)(ws + F_FEATS);  // feats f32 dead from here
  attn_part_kernel<32><<<dim3(36, 4, KS), blk, 0, stream>>>(Bft, Bft, Dfb, Opart, lp);
  __bf16* att1_t = (__bf16*)(ws + F_AT1T);
  combine32_kernel<<<dim3(72, 1, 4), blk, 0, stream>>>(Opart, lp, att1_t);
  __bf16* comb_t = (__bf16*)(ws + F_CT);
  gemm_mfma_kernel<32, 0, 1, 1, 0, 0><<<dim3(144, 4, 1), blk, 0, stream>>>(
      att1_t, nullptr, wbase + W_PS, ps_b, ps_b, nullptr, ws + F_REC, ws + F_REC,
      comb_t, comb_t, nullptr, 128, 128, 128, 1.f, 1.f, 1.f);

  // --- final attention: ONE 3-segment Q|K2|V2 GEMM, flash-LDS attn ---
  __bf16* Qt = (__bf16*)(ws + F_XR);
  __bf16* K2t = (__bf16*)(ws + F_XT);
  __bf16* V2b = (__bf16*)(ws + F_V);  // sf_t dead after lb/ld gemm
  gemm_mfma_kernel<128, 0, 1, 1, 2, 0><<<dim3(144, 4, 3), blk, 0, stream>>>(
      comb_t, nullptr, wbase + W_PQK, pq_b, k_b, v_b, nullptr, nullptr,
      Qt, K2t, V2b, 128, 256, 384, 0.08838834764831845f, 1.f, 1.f);
  attn_part_kernel<128><<<dim3(36, 4, KS), blk, 0, stream>>>(Qt, K2t, V2b, Opart, lp);
  float* x1 = ws + F_R;                 // dense_t dead after sn1
  __bf16* x1_t = (__bf16*)(ws + F_CT);  // comb_t dead after QKV gemm
  combine128_kernel<<<dim3(72, 4, 4), blk, 0, stream>>>(Opart, lp, x, x1, x1_t);

  // --- FFN tail ---
  __bf16* h_t = (__bf16*)(ws + F_FEATS);  // Op partials dead after combine
  gemm_mfma_kernel<128, 3, 1, 1, 0, 0><<<dim3(144, 4, 4), blk, 0, stream>>>(
      x1_t, nullptr, wbase + W_FC1, fc1_b, fc1_b, nullptr, nullptr, nullptr,
      h_t, h_t, nullptr, 512, 512, 512, 1.f, 1.f, 1.f);
  gemm_mfma_kernel<512, 0, 0, 0, 0, 0><<<dim3(144, 4, 1), blk, 0, stream>>>(
      h_t, nullptr, wbase + W_FC2, fc2_b, fc2_b, nullptr, x1, x1,
      outp, outp, nullptr, 128, 128, 128, 1.f, 1.f, 1.f);
}

// Round 3
// 412.722 us; speedup vs baseline: 1.1923x; 1.0449x over previous
//
#include <hip/hip_runtime.h>
#include <math.h>

#define BB 4
#define CC 128
#define HH 48
#define WW 48
#define NSP (HH*WW)          // 2304
#define DCC 256
#define BCN (BB*CC*NSP)      // 1179648
#define KS 6                 // attention key-splits

typedef float f32x4 __attribute__((ext_vector_type(4)));
typedef __bf16 bf16x8 __attribute__((ext_vector_type(8)));
typedef __bf16 bf16x4 __attribute__((ext_vector_type(4)));

__device__ __forceinline__ float sigmf(float v) { return 1.0f / (1.0f + __expf(-v)); }

// ---------------- merged prep: weight cvt (13) + conv3x3 pack (4) + x-stats + x dual-transpose ----------------
struct Prep {
  const float* wsrc[13];
  int wlen[13];
  int woff[13];
  const float* psrc[4];
  int pcin[4];
  int poff[4];
  const float* x;
  float* sums;
  float* sums2;
  __bf16* x_t;
  __bf16* xrope_t;
};
__global__ __launch_bounds__(256) void prep_kernel(Prep a, __bf16* __restrict__ wdst,
                                                   __bf16* __restrict__ pdst) {
  __shared__ float lds[32][33];
  __shared__ float rs[4], rs2[4];
  int g = blockIdx.y;
  int idx = blockIdx.x * 256 + threadIdx.x;
  if (g < 13) {
    if (idx < a.wlen[g]) wdst[a.woff[g] + idx] = (__bf16)a.wsrc[g][idx];
  } else if (g < 17) {
    int L = g - 13;
    int cin = a.pcin[L];
    if (idx < 9 * 32 * cin) {
      int c = idx % cin;
      int o = (idx / cin) % 32;
      int tap = idx / (cin * 32);
      pdst[a.poff[L] + idx] = (__bf16)a.psrc[L][((size_t)o * cin + c) * 9 + tap];
    }
  } else if (g == 17) {
    // x-channel BN stats: one block per channel (plain stores, no atomics)
    int c = blockIdx.x;
    if (c >= 128) return;
    float s = 0.f, s2 = 0.f;
    for (int i = threadIdx.x; i < BB * NSP; i += 256) {
      int b = i / NSP, n = i % NSP;
      float v = a.x[((size_t)b * 128 + c) * NSP + n];
      s += v;
      s2 += v * v;
    }
#pragma unroll
    for (int off = 32; off > 0; off >>= 1) {
      s += __shfl_down(s, off);
      s2 += __shfl_down(s2, off);
    }
    int wid = threadIdx.x >> 6;
    if ((threadIdx.x & 63) == 0) { rs[wid] = s; rs2[wid] = s2; }
    __syncthreads();
    if (threadIdx.x == 0) {
      a.sums[c] = rs[0] + rs[1] + rs[2] + rs[3];
      a.sums2[c] = rs2[0] + rs2[1] + rs2[2] + rs2[3];
    }
  } else {
    // dual transpose x -> x_t (plain) + xrope_t (RoPE), LDS-tiled
    int T = (g - 18) * 256 + blockIdx.x;
    if (T >= 1152) return;
    int b = T / 288;
    int r = T % 288;
    int c0 = (r / 72) * 32;
    int n0 = (r % 72) * 32;
    int tid = threadIdx.x;
    int nn = tid & 31, cs = tid >> 5;
#pragma unroll
    for (int j = 0; j < 4; ++j) {
      int cc = c0 + cs * 4 + j;
      lds[cs * 4 + j][nn] = a.x[((size_t)b * 128 + cc) * NSP + n0 + nn];
    }
    __syncthreads();
    int c = tid & 31, ns = tid >> 5;
#pragma unroll
    for (int j = 0; j < 4; ++j) {
      int n2 = ns * 4 + j;
      float pv = lds[c][n2];
      a.x_t[((size_t)b * NSP + n0 + n2) * 128 + c0 + c] = (__bf16)pv;
      int gc = c0 + c;
      int i = gc >> 1;
      float re = lds[c & ~1][n2];
      float im = lds[c | 1][n2];
      int n = n0 + n2;
      int h = n / WW, w = n % WW;
      float theta = __expf(-9.2103403719761836f * ((float)i) / 64.0f);
      float pos = (float)(h + w) * theta;
      float cs_ = cosf(pos), sn_ = sinf(pos);
      float vr_ = (gc & 1) ? (re * sn_ + im * cs_) : (re * cs_ - im * sn_);
      a.xrope_t[((size_t)b * NSP + n0 + n2) * 128 + c0 + c] = (__bf16)vr_;
    }
  }
}

// ---------------- fused k|v|r GEMM + full rwkv epilogue (no intermediate buffers) ----------------
__global__ __launch_bounds__(256) void kvr_kernel(
    const __bf16* __restrict__ xrope_t, const __bf16* __restrict__ x_t,
    const __bf16* __restrict__ wk, const __bf16* __restrict__ wvp,
    const __bf16* __restrict__ wr,
    const float* __restrict__ k_b, const float* __restrict__ v_b,
    const float* __restrict__ r_b, const float* __restrict__ u,
    float* __restrict__ kden, float* __restrict__ knum, float* __restrict__ rec) {
  int tid = threadIdx.x;
  int wv = tid >> 6, lane = tid & 63;
  int m15 = lane & 15, quad = lane >> 4;
  int b = blockIdx.y;
  int n0 = blockIdx.x * 16;
  int o0 = wv * 32;
  int n = n0 + m15;
  const __bf16* brr = xrope_t + ((size_t)b * NSP + n) * 128 + quad * 8;
  const __bf16* brx = x_t + ((size_t)b * NSP + n) * 128 + quad * 8;
  const __bf16* ak0 = wk + (size_t)(o0 + m15) * 128 + quad * 8;
  const __bf16* ak1 = wk + (size_t)(o0 + 16 + m15) * 128 + quad * 8;
  const __bf16* av0 = wvp + (size_t)(o0 + m15) * 128 + quad * 8;
  const __bf16* av1 = wvp + (size_t)(o0 + 16 + m15) * 128 + quad * 8;
  const __bf16* ar0 = wr + (size_t)(o0 + m15) * 128 + quad * 8;
  const __bf16* ar1 = wr + (size_t)(o0 + 16 + m15) * 128 + quad * 8;
  f32x4 fk[2], fv[2], fr[2];
#pragma unroll
  for (int t = 0; t < 2; ++t) {
    fk[t] = (f32x4){0.f, 0.f, 0.f, 0.f};
    fv[t] = (f32x4){0.f, 0.f, 0.f, 0.f};
    fr[t] = (f32x4){0.f, 0.f, 0.f, 0.f};
  }
#pragma unroll
  for (int kc = 0; kc < 128; kc += 32) {
    bf16x8 br_ = *(const bf16x8*)(brr + kc);
    bf16x8 bx_ = *(const bf16x8*)(brx + kc);
    fk[0] = __builtin_amdgcn_mfma_f32_16x16x32_bf16(*(const bf16x8*)(ak0 + kc), br_, fk[0], 0, 0, 0);
    fk[1] = __builtin_amdgcn_mfma_f32_16x16x32_bf16(*(const bf16x8*)(ak1 + kc), br_, fk[1], 0, 0, 0);
    fv[0] = __builtin_amdgcn_mfma_f32_16x16x32_bf16(*(const bf16x8*)(av0 + kc), br_, fv[0], 0, 0, 0);
    fv[1] = __builtin_amdgcn_mfma_f32_16x16x32_bf16(*(const bf16x8*)(av1 + kc), br_, fv[1], 0, 0, 0);
    fr[0] = __builtin_amdgcn_mfma_f32_16x16x32_bf16(*(const bf16x8*)(ar0 + kc), bx_, fr[0], 0, 0, 0);
    fr[1] = __builtin_amdgcn_mfma_f32_16x16x32_bf16(*(const bf16x8*)(ar1 + kc), bx_, fr[1], 0, 0, 0);
  }
#pragma unroll
  for (int t = 0; t < 2; ++t) {
#pragma unroll
    for (int reg = 0; reg < 4; ++reg) {
      int ol = o0 + t * 16 + quad * 4 + reg;
      float kk = fk[t][reg] + k_b[ol];
      float vv = fv[t][reg] + v_b[ol];
      float rr = sigmf(fr[t][reg] + r_b[ol]);
      float eu = __expf(u[ol]);
      size_t idx = ((size_t)b * 128 + ol) * NSP + n;
      float nv = kk * vv, tt = eu * kk;
      kden[idx] = kk;
      knum[idx] = nv;
      rec[idx] = rr * ((nv + tt * vv) / (kk + tt));
    }
  }
}

// ---------------- segmented-epilogue MFMA GEMM (up to 3 segments) ----------------
// OUT: 0 f32 planar, 1 bf16 transposed, 2 bf16 planar, 3 per-(b,ch) partial sums (tau).
// ACT: 0 none, 1 relu, 2 sigmoid, 3 relu^2.
// SPLITB: B-operand ch<128 from in_t (stride 128), ch>=128 from in_t2 (stride 128).
template <int OUT>
__device__ __forceinline__ void gemm_store(void* outp, int b, int n, int Oseg,
                                           int obase, int quad, const float* vr) {
  if (OUT == 0) {
    float* op = (float*)outp;
#pragma unroll
    for (int reg = 0; reg < 4; ++reg)
      op[((size_t)b * Oseg + obase + quad * 4 + reg) * NSP + n] = vr[reg];
  } else if (OUT == 1) {
    __bf16* op = (__bf16*)outp;
    bf16x4 pk;
#pragma unroll
    for (int reg = 0; reg < 4; ++reg) pk[reg] = (__bf16)vr[reg];
    *(bf16x4*)(op + ((size_t)b * NSP + n) * Oseg + obase + quad * 4) = pk;
  } else {
    __bf16* op = (__bf16*)outp;
#pragma unroll
    for (int reg = 0; reg < 4; ++reg)
      op[((size_t)b * Oseg + obase + quad * 4 + reg) * NSP + n] = (__bf16)vr[reg];
  }
}

template <int K, int ACT, int OUT0, int OUT1, int OUT2, int SPLITB>
__global__ __launch_bounds__(256) void gemm_mfma_kernel(
    const __bf16* __restrict__ in_t, const __bf16* __restrict__ in_t2,
    const __bf16* __restrict__ wb,
    const float* __restrict__ bias0, const float* __restrict__ bias1,
    const float* __restrict__ bias2,
    const float* __restrict__ add0, const float* __restrict__ add1,
    void* __restrict__ out0, void* __restrict__ out1, void* __restrict__ out2,
    int osplit, int osplit2, int Ototal, float sc0, float sc1, float sc2) {
  int tid = threadIdx.x;
  int wv = tid >> 6, lane = tid & 63;
  int m15 = lane & 15, quad = lane >> 4;
  int b = blockIdx.y;
  int n0 = blockIdx.x * 16;
  int wpb = blockDim.x >> 6;
  int o0 = (blockIdx.z * wpb + wv) * 32;
  if (o0 >= Ototal) return;
  int n = n0 + m15;
  const __bf16* brow = in_t + ((size_t)b * NSP + n) * (SPLITB ? 128 : K) + quad * 8;
  const __bf16* brow2 = SPLITB ? (in_t2 + ((size_t)b * NSP + n) * 128 + quad * 8) : nullptr;
  const __bf16* a0p = wb + (size_t)(o0 + m15) * K + quad * 8;
  const __bf16* a1p = wb + (size_t)(o0 + 16 + m15) * K + quad * 8;
  f32x4 of0 = (f32x4){0.f, 0.f, 0.f, 0.f};
  f32x4 of1 = (f32x4){0.f, 0.f, 0.f, 0.f};
#pragma unroll
  for (int kc = 0; kc < K; kc += 32) {
    bf16x8 bfr;
    if constexpr (SPLITB) {
      bfr = (kc < 128) ? *(const bf16x8*)(brow + kc) : *(const bf16x8*)(brow2 + (kc - 128));
    } else {
      bfr = *(const bf16x8*)(brow + kc);
    }
    bf16x8 a0 = *(const bf16x8*)(a0p + kc);
    bf16x8 a1 = *(const bf16x8*)(a1p + kc);
    of0 = __builtin_amdgcn_mfma_f32_16x16x32_bf16(a0, bfr, of0, 0, 0, 0);
    of1 = __builtin_amdgcn_mfma_f32_16x16x32_bf16(a1, bfr, of1, 0, 0, 0);
  }
  int seg = (o0 >= osplit2) ? 2 : (o0 >= osplit) ? 1 : 0;
  int segb = (seg == 2) ? osplit2 : (seg == 1) ? osplit : 0;
  int sege = (seg == 2) ? Ototal : (seg == 1) ? osplit2 : osplit;
  int Oseg = sege - segb;
  int ol0 = o0 - segb;
  const float* bias = (seg == 2) ? bias2 : (seg == 1) ? bias1 : bias0;
  const float* add = (seg == 2) ? nullptr : (seg == 1) ? add1 : add0;
  void* outp = (seg == 2) ? out2 : (seg == 1) ? out1 : out0;
  float sc = (seg == 2) ? sc2 : (seg == 1) ? sc1 : sc0;
#pragma unroll
  for (int t = 0; t < 2; ++t) {
    f32x4 acc = t ? of1 : of0;
    float vr[4];
#pragma unroll
    for (int reg = 0; reg < 4; ++reg) {
      int ol = ol0 + t * 16 + quad * 4 + reg;
      float v = acc[reg] + bias[ol];
      if (ACT == 1) v = fmaxf(v, 0.0f);
      else if (ACT == 2) v = sigmf(v);
      else if (ACT == 3) { v = fmaxf(v, 0.0f); v = v * v; }
      v *= sc;
      if (add) v += add[((size_t)b * Oseg + ol) * NSP + n];
      vr[reg] = v;
    }
    if constexpr (OUT0 == 3) {
      // per-(b,ch) partial row-sum over this block's 16 n (contention-free store)
#pragma unroll
      for (int reg = 0; reg < 4; ++reg) {
        float sv = vr[reg];
        sv += __shfl_xor(sv, 1);
        sv += __shfl_xor(sv, 2);
        sv += __shfl_xor(sv, 4);
        sv += __shfl_xor(sv, 8);
        if (m15 == 0)
          ((float*)out0)[((size_t)(b * DCC + ol0 + t * 16 + quad * 4 + reg)) * 144 +
                         blockIdx.x] = sv;
      }
    } else {
      if (seg == 0) gemm_store<OUT0>(outp, b, n, Oseg, ol0 + t * 16, quad, vr);
      else if (seg == 1) gemm_store<OUT1>(outp, b, n, Oseg, ol0 + t * 16, quad, vr);
      else gemm_store<OUT2>(outp, b, n, Oseg, ol0 + t * 16, quad, vr);
    }
  }
}

// ---------------- lb|ld GEMM with inline spike-fn B (sf never materialized) ----------------
__global__ __launch_bounds__(128) void lbld_sf_kernel(
    const __bf16* __restrict__ x_t, const __bf16* __restrict__ dense_t,
    const float* __restrict__ taupart, const __bf16* __restrict__ wlb,
    const float* __restrict__ lb_b, const float* __restrict__ ld_b,
    __bf16* __restrict__ Bft, __bf16* __restrict__ Dfb) {
  __shared__ float ef[256];  // exp(-1/(tau+eps)) - 1 per channel
  int tid = threadIdx.x;
  int b = blockIdx.y;
  for (int ch = tid; ch < 256; ch += 128) {
    const f32x4* tp = (const f32x4*)(taupart + ((size_t)(b * DCC + ch)) * 144);
    f32x4 s4 = (f32x4){0.f, 0.f, 0.f, 0.f};
#pragma unroll
    for (int j = 0; j < 36; ++j) s4 += tp[j];
    float tv = (s4.x + s4.y + s4.z + s4.w) * (1.0f / (float)NSP);
    ef[ch] = __expf(-1.0f / (tv + 1e-6f)) - 1.0f;
  }
  __syncthreads();
  int wv = tid >> 6, lane = tid & 63;
  int m15 = lane & 15, quad = lane >> 4;
  int n0 = blockIdx.x * 16;
  int o0 = wv * 32;
  int n = n0 + m15;
  const __bf16* bx = x_t + ((size_t)b * NSP + n) * 128 + quad * 8;
  const __bf16* bd = dense_t + ((size_t)b * NSP + n) * 128 + quad * 8;
  const __bf16* a0p = wlb + (size_t)(o0 + m15) * 256 + quad * 8;
  const __bf16* a1p = wlb + (size_t)(o0 + 16 + m15) * 256 + quad * 8;
  f32x4 of0 = (f32x4){0.f, 0.f, 0.f, 0.f};
  f32x4 of1 = (f32x4){0.f, 0.f, 0.f, 0.f};
#pragma unroll
  for (int kc = 0; kc < 256; kc += 32) {
    bf16x8 raw = (kc < 128) ? *(const bf16x8*)(bx + kc) : *(const bf16x8*)(bd + (kc - 128));
    bf16x8 sfv;
#pragma unroll
    for (int j = 0; j < 8; ++j) {
      float df = (float)raw[j];
      float sp = sigmf((df - 1.0f) * 5.0f);
      sfv[j] = (__bf16)(df * (1.0f + sp * ef[kc + quad * 8 + j]));
    }
    bf16x8 a0 = *(const bf16x8*)(a0p + kc);
    bf16x8 a1 = *(const bf16x8*)(a1p + kc);
    of0 = __builtin_amdgcn_mfma_f32_16x16x32_bf16(a0, sfv, of0, 0, 0, 0);
    of1 = __builtin_amdgcn_mfma_f32_16x16x32_bf16(a1, sfv, of1, 0, 0, 0);
  }
  if (o0 == 0) {  // lb -> Bft (B,N,32) transposed
#pragma unroll
    for (int t = 0; t < 2; ++t) {
      f32x4 acc = t ? of1 : of0;
      bf16x4 pk;
#pragma unroll
      for (int reg = 0; reg < 4; ++reg) pk[reg] = (__bf16)(acc[reg] + lb_b[t * 16 + quad * 4 + reg]);
      *(bf16x4*)(Bft + ((size_t)b * NSP + n) * 32 + t * 16 + quad * 4) = pk;
    }
  } else {  // ld -> Dfb (B,32,N) planar
#pragma unroll
    for (int t = 0; t < 2; ++t) {
      f32x4 acc = t ? of1 : of0;
#pragma unroll
      for (int reg = 0; reg < 4; ++reg) {
        int ol = t * 16 + quad * 4 + reg;
        Dfb[((size_t)b * 32 + ol) * NSP + n] = (__bf16)(acc[reg] + ld_b[ol]);
      }
    }
  }
}

// ---------------- tiled BN+ReLU -> ht (B,N,DCC-stride) bf16 ----------------
__global__ __launch_bounds__(256) void bnrelu_t_kernel(
    const float* __restrict__ src, size_t bstride, int gcoff,
    const float* __restrict__ sums, const float* __restrict__ sums2,
    const float* __restrict__ cpart,
    const float* __restrict__ g, const float* __restrict__ bb,
    __bf16* __restrict__ ht) {
  __shared__ float lds[32][33];
  __shared__ float fst[64];
  int b = blockIdx.z;
  int n0 = blockIdx.x * 32;
  int c0 = blockIdx.y * 32;
  int tid = threadIdx.x;

  if (cpart) {
    __shared__ float tmp[4][64];
    int r = tid & 63, sl = tid >> 6;
    const float* cp = cpart + (size_t)r * 576 + sl * 144;
    float a = 0.f;
#pragma unroll 4
    for (int j = 0; j < 144; ++j) a += cp[j];
    tmp[sl][r] = a;
    __syncthreads();
    if (tid < 64) fst[tid] = tmp[0][tid] + tmp[1][tid] + tmp[2][tid] + tmp[3][tid];
    __syncthreads();
  }

  int nn = tid & 31, cs = tid >> 5;
#pragma unroll
  for (int j = 0; j < 4; ++j) {
    int cc = c0 + cs * 4 + j;
    lds[cs * 4 + j][nn] = src[(size_t)b * bstride + (size_t)cc * NSP + n0 + nn];
  }
  __syncthreads();
  int c = tid & 31, ns = tid >> 5;
  int gc = gcoff + c0 + c;
  const float inv = 1.0f / (float)(BB * NSP);
  float S = cpart ? fst[c] : sums[gc];
  float S2 = cpart ? fst[32 + c] : sums2[gc];
  float m = S * inv;
  float var = S2 * inv - m * m;
  float sc_ = rsqrtf(var + 1e-5f) * g[gc];
  float sh_ = bb[gc] - m * sc_;
#pragma unroll
  for (int j = 0; j < 4; ++j) {
    int n2 = ns * 4 + j;
    float v = fmaxf(lds[c][n2] * sc_ + sh_, 0.0f);
    ht[((size_t)b * NSP + n0 + n2) * DCC + gc] = (__bf16)v;
  }
}

// ---------------- conv3x3: 4 waves split tap x K chunks, LDS partial reduce ----------------
template <int Cin>
__global__ __launch_bounds__(256) void conv3x3_mfma_kernel(
    const __bf16* __restrict__ ht, const __bf16* __restrict__ wb,
    const float* __restrict__ cb, float* __restrict__ feats, int cout0,
    __bf16* __restrict__ dense_t, float* __restrict__ cpart) {
  constexpr int KCin = Cin / 32;
  __shared__ float red[4][64][8];
  int tid = threadIdx.x;
  int wv = tid >> 6, lane = tid & 63;
  int m15 = lane & 15, quad = lane >> 4;
  int b = blockIdx.y;
  int n0 = blockIdx.x * 16;
  int n = n0 + m15;
  int h = n / WW, w = n % WW;
  f32x4 of0 = (f32x4){0.f, 0.f, 0.f, 0.f};
  f32x4 of1 = (f32x4){0.f, 0.f, 0.f, 0.f};
  const __bf16* htb = ht + (size_t)b * NSP * DCC;
  const bf16x8 zf = {};
  for (int ci = wv; ci < 9 * KCin; ci += 4) {
    int tap = ci / KCin;
    int kc = (ci % KCin) * 32;
    int dh = tap / 3 - 1, dw = tap % 3 - 1;
    bool valid = ((unsigned)(h + dh) < HH) && ((unsigned)(w + dw) < WW);
    int pa = valid ? (n + dh * WW + dw) : 0;
    bf16x8 bfr = *(const bf16x8*)(htb + (size_t)pa * DCC + kc + quad * 8);
    if (!valid) bfr = zf;
    const __bf16* wt = wb + (size_t)tap * 32 * Cin + kc + quad * 8;
    bf16x8 a0 = *(const bf16x8*)(wt + (size_t)m15 * Cin);
    bf16x8 a1 = *(const bf16x8*)(wt + (size_t)(16 + m15) * Cin);
    of0 = __builtin_amdgcn_mfma_f32_16x16x32_bf16(a0, bfr, of0, 0, 0, 0);
    of1 = __builtin_amdgcn_mfma_f32_16x16x32_bf16(a1, bfr, of1, 0, 0, 0);
  }
  float* myred = red[wv][lane];
#pragma unroll
  for (int reg = 0; reg < 4; ++reg) {
    myred[reg] = of0[reg];
    myred[4 + reg] = of1[reg];
  }
  __syncthreads();
  if (wv == 0) {
    int dloc = cout0 - 128;
    __bf16* dt = dense_t + ((size_t)b * NSP + n) * 128 + dloc;
#pragma unroll
    for (int reg = 0; reg < 4; ++reg) {
      int o = quad * 4 + reg;
      float v0 = red[0][lane][reg] + red[1][lane][reg] + red[2][lane][reg] +
                 red[3][lane][reg] + cb[o];
      float v1 = red[0][lane][4 + reg] + red[1][lane][4 + reg] + red[2][lane][4 + reg] +
                 red[3][lane][4 + reg] + cb[16 + o];
      feats[((size_t)b * DCC + cout0 + o) * NSP + n] = v0;
      feats[((size_t)b * DCC + cout0 + 16 + o) * NSP + n] = v1;
      dt[o] = (__bf16)v0;
      dt[16 + o] = (__bf16)v1;
      if (cpart) {
        float a0 = v0, q0 = v0 * v0, a1 = v1, q1 = v1 * v1;
#pragma unroll
        for (int mk = 1; mk < 16; mk <<= 1) {
          a0 += __shfl_xor(a0, mk);
          q0 += __shfl_xor(q0, mk);
          a1 += __shfl_xor(a1, mk);
          q1 += __shfl_xor(q1, mk);
        }
        if (m15 == 0) {
          int pidx = blockIdx.y * 144 + blockIdx.x;
          cpart[(size_t)o * 576 + pidx] = a0;
          cpart[(size_t)(32 + o) * 576 + pidx] = q0;
          cpart[(size_t)(16 + o) * 576 + pidx] = a1;
          cpart[(size_t)(48 + o) * 576 + pidx] = q1;
        }
      }
    }
  }
}

// ---------------- flash-LDS MFMA attention: 4 waves share K/V tiles via LDS ----------------
template <int CD>
__global__ __launch_bounds__(256) void attn_part_kernel(
    const __bf16* __restrict__ Qt, const __bf16* __restrict__ Kt,
    const __bf16* __restrict__ Vb, __bf16* __restrict__ Op,
    float* __restrict__ lp) {
  constexpr int NC = CD / 16;
  constexpr int KC = CD / 32;
  constexpr int KEYS = NSP / KS;  // 384
  constexpr int KP = CD + 4;
  constexpr int VP = 36;
  __shared__ __bf16 kl[32][KP];
  __shared__ __bf16 vl[CD][VP];
  __shared__ float pt[4][16][36];
  int tid = threadIdx.x;
  int wv = tid >> 6, lane = tid & 63;
  int m15 = lane & 15, quad = lane >> 4;
  int b = blockIdx.y, ks = blockIdx.z;
  int n0 = blockIdx.x * 64 + wv * 16;

  bf16x8 qf[KC];
  const __bf16* qrow = Qt + ((size_t)b * NSP + n0 + m15) * CD + quad * 8;
#pragma unroll
  for (int kc = 0; kc < KC; ++kc) qf[kc] = *(const bf16x8*)(qrow + kc * 32);

  f32x4 of[NC];
#pragma unroll
  for (int i = 0; i < NC; ++i) of[i] = (f32x4){0.f, 0.f, 0.f, 0.f};
  float l0 = 0.f, l1 = 0.f, l2 = 0.f, l3 = 0.f;

  const __bf16* Kb = Kt + (size_t)b * NSP * CD;
  const __bf16* Vbb = Vb + (size_t)b * CD * NSP;
  float(*ptw)[36] = pt[wv];

  for (int m0 = ks * KEYS; m0 < (ks + 1) * KEYS; m0 += 32) {
    __syncthreads();
    for (int i = tid; i < 32 * CD / 8; i += 256) {
      int row = i / (CD / 8);
      int cc8 = (i % (CD / 8)) * 8;
      *(bf16x8*)&kl[row][cc8] = *(const bf16x8*)(Kb + (size_t)(m0 + row) * CD + cc8);
    }
    for (int i = tid; i < CD * 4; i += 256) {
      int ch = i / 4;
      int k8 = (i % 4) * 8;
      *(bf16x8*)&vl[ch][k8] = *(const bf16x8*)(Vbb + (size_t)ch * NSP + m0 + k8);
    }
    __syncthreads();
    f32x4 s[2];
#pragma unroll
    for (int t = 0; t < 2; ++t) {
      f32x4 acc = (f32x4){0.f, 0.f, 0.f, 0.f};
#pragma unroll
      for (int kc = 0; kc < KC; ++kc) {
        bf16x8 kf = *(const bf16x8*)&kl[t * 16 + m15][kc * 32 + quad * 8];
        acc = __builtin_amdgcn_mfma_f32_16x16x32_bf16(qf[kc], kf, acc, 0, 0, 0);
      }
      s[t] = acc;
    }
#pragma unroll
    for (int t = 0; t < 2; ++t) {
      float e0 = __expf(s[t].x), e1 = __expf(s[t].y), e2 = __expf(s[t].z), e3 = __expf(s[t].w);
      l0 += e0; l1 += e1; l2 += e2; l3 += e3;
      ptw[quad * 4 + 0][t * 16 + m15] = e0;
      ptw[quad * 4 + 1][t * 16 + m15] = e1;
      ptw[quad * 4 + 2][t * 16 + m15] = e2;
      ptw[quad * 4 + 3][t * 16 + m15] = e3;
    }
    const float* prow = &ptw[m15][quad * 8];
    f32x4 pa = *(const f32x4*)(prow);
    f32x4 pb = *(const f32x4*)(prow + 4);
    bf16x8 pf;
    pf[0] = (__bf16)pa.x; pf[1] = (__bf16)pa.y; pf[2] = (__bf16)pa.z; pf[3] = (__bf16)pa.w;
    pf[4] = (__bf16)pb.x; pf[5] = (__bf16)pb.y; pf[6] = (__bf16)pb.z; pf[7] = (__bf16)pb.w;
#pragma unroll
    for (int ct = 0; ct < NC; ++ct) {
      bf16x8 vf = *(const bf16x8*)&vl[ct * 16 + m15][quad * 8];
      of[ct] = __builtin_amdgcn_mfma_f32_16x16x32_bf16(pf, vf, of[ct], 0, 0, 0);
    }
  }

#pragma unroll
  for (int off = 1; off < 16; off <<= 1) {
    l0 += __shfl_xor(l0, off);
    l1 += __shfl_xor(l1, off);
    l2 += __shfl_xor(l2, off);
    l3 += __shfl_xor(l3, off);
  }
  float* lpb = lp + (size_t)(ks * BB + b) * NSP + n0;
  if (m15 == 0) {
    lpb[quad * 4 + 0] = l0;
    lpb[quad * 4 + 1] = l1;
    lpb[quad * 4 + 2] = l2;
    lpb[quad * 4 + 3] = l3;
  }
  __bf16* Ob = Op + (size_t)(ks * BB + b) * CD * NSP;
#pragma unroll
  for (int ct = 0; ct < NC; ++ct) {
    bf16x4 pk;
#pragma unroll
    for (int reg = 0; reg < 4; ++reg) pk[reg] = (__bf16)of[ct][reg];
    *(bf16x4*)(Ob + (size_t)(ct * 16 + m15) * NSP + n0 + quad * 4) = pk;
  }
}

// combine partials for CD=32 -> att1_t (B,N,32) bf16
__global__ __launch_bounds__(256) void combine32_kernel(const __bf16* __restrict__ Op,
                                                        const float* __restrict__ lp,
                                                        __bf16* __restrict__ att1_t) {
  __shared__ float lds[32][33];
  int b = blockIdx.z;
  int n0 = blockIdx.x * 32;
  int tid = threadIdx.x;
  int nn = tid & 31, cs = tid >> 5;
  float ltot = 0.f;
#pragma unroll
  for (int ks = 0; ks < KS; ++ks) ltot += lp[(size_t)(ks * BB + b) * NSP + n0 + nn];
  float linv = 1.0f / ltot;
#pragma unroll
  for (int j = 0; j < 4; ++j) {
    int cc = cs * 4 + j;
    float s = 0.f;
#pragma unroll
    for (int ks = 0; ks < KS; ++ks)
      s += (float)Op[((size_t)(ks * BB + b) * 32 + cc) * NSP + n0 + nn];
    lds[cc][nn] = s * linv;
  }
  __syncthreads();
  int c = tid & 31, ns = tid >> 5;
#pragma unroll
  for (int j = 0; j < 4; ++j) {
    int n2 = ns * 4 + j;
    att1_t[((size_t)b * NSP + n0 + n2) * 32 + c] = (__bf16)lds[c][n2];
  }
}

// combine partials for CD=128, + x residual -> x1 (f32 planar) AND x1_t (bf16 transposed)
__global__ __launch_bounds__(256) void combine128_kernel(
    const __bf16* __restrict__ Op, const float* __restrict__ lp,
    const float* __restrict__ x, float* __restrict__ x1, __bf16* __restrict__ x1_t) {
  __shared__ float lds[32][33];
  int b = blockIdx.z;
  int n0 = blockIdx.x * 32;
  int c0 = blockIdx.y * 32;
  int tid = threadIdx.x;
  int nn = tid & 31, cs = tid >> 5;
  float ltot = 0.f;
#pragma unroll
  for (int ks = 0; ks < KS; ++ks) ltot += lp[(size_t)(ks * BB + b) * NSP + n0 + nn];
  float linv = 1.0f / ltot;
#pragma unroll
  for (int j = 0; j < 4; ++j) {
    int gc = c0 + cs * 4 + j;
    float s = 0.f;
#pragma unroll
    for (int ks = 0; ks < KS; ++ks)
      s += (float)Op[((size_t)(ks * BB + b) * CC + gc) * NSP + n0 + nn];
    float v = s * linv + x[((size_t)b * CC + gc) * NSP + n0 + nn];
    lds[cs * 4 + j][nn] = v;
    x1[((size_t)b * CC + gc) * NSP + n0 + nn] = v;
  }
  __syncthreads();
  int c = tid & 31, ns = tid >> 5;
#pragma unroll
  for (int j = 0; j < 4; ++j) {
    int n2 = ns * 4 + j;
    x1_t[((size_t)b * NSP + n0 + n2) * CC + c0 + c] = (__bf16)lds[c][n2];
  }
}

// ---------------- host ----------------
extern "C" void kernel_launch(void* const* d_in, const int* in_sizes, int n_in,
                              void* d_out, int out_size, void* d_ws, size_t ws_size,
                              hipStream_t stream) {
  const float* x = (const float*)d_in[0];
  const float* r_w = (const float*)d_in[1];
  const float* r_b = (const float*)d_in[2];
  const float* k_w = (const float*)d_in[3];
  const float* k_b = (const float*)d_in[4];
  const float* v_w = (const float*)d_in[5];
  const float* v_b = (const float*)d_in[6];
  // d_in[7..10]: wc1/wc2 — dead code (multiplied by zeros in reference)
  const float* u = (const float*)d_in[11];
  const float* sn1_w = (const float*)d_in[12];
  const float* sn1_b = (const float*)d_in[13];
  const float* sn2_w = (const float*)d_in[14];
  const float* sn2_b = (const float*)d_in[15];
  const float* lb_w = (const float*)d_in[16];
  const float* lb_b = (const float*)d_in[17];
  const float* ld_w = (const float*)d_in[18];
  const float* ld_b = (const float*)d_in[19];
  const float* ps_w = (const float*)d_in[20];
  const float* ps_b = (const float*)d_in[21];
  const float* pq_w = (const float*)d_in[22];
  const float* pq_b = (const float*)d_in[23];
  const float* fc1_w = (const float*)d_in[24];
  const float* fc1_b = (const float*)d_in[25];
  const float* fc2_w = (const float*)d_in[26];
  const float* fc2_b = (const float*)d_in[27];
  const float* db_g[4] = {(const float*)d_in[28], (const float*)d_in[32],
                          (const float*)d_in[36], (const float*)d_in[40]};
  const float* db_b[4] = {(const float*)d_in[29], (const float*)d_in[33],
                          (const float*)d_in[37], (const float*)d_in[41]};
  const float* db_w[4] = {(const float*)d_in[30], (const float*)d_in[34],
                          (const float*)d_in[38], (const float*)d_in[42]};
  const float* db_cb[4] = {(const float*)d_in[31], (const float*)d_in[35],
                           (const float*)d_in[39], (const float*)d_in[43]};

  float* outp = (float*)d_out;           // out  (B,C,H,W)
  float* knum = outp + BCN;              // new_num = k*v
  float* kden = outp + 2 * (size_t)BCN;  // new_den = k

  float* ws = (float*)d_ws;
  // region map (f32 slots)
  const size_t F_FEATS = 0;         // feats f32 -> Op partials -> h_t bf16
  const size_t F_REC = 4718592;     // rec f32 (1179648)
  const size_t F_V = 5898240;       // ht bf16 -> V2b bf16 (1179648)
  const size_t F_R = 7077888;       // dense_t bf16 (589824) -> x1 f32 (1179648)
  const size_t F_XR = 8257536;      // xrope_t bf16 -> z1_t -> Qt (589824)
  const size_t F_XT = 8847360;      // x_t bf16 -> Bft -> K2t (589824)
  const size_t F_DFB = 9437184;     // Dfb bf16 (147456)
  const size_t F_AT1T = 9584640;    // att1_t bf16 (147456)
  const size_t F_CT = 9732096;      // combined_t bf16 -> x1_t bf16 (589824)
  const size_t F_LP = 10321920;     // lp f32 (KS*B*NSP = 55296)
  const size_t F_WB = 10434048;     // conv1x1 weights bf16 (282624 bf16 = 141312 slots)
  const size_t F_WB3 = 10575360;    // conv3x3 packed weights bf16 (202752 bf16 = 101376 slots)
  const size_t F_STATS = 10676736;  // sums[256] sums2[256]
  const size_t F_CPART = 10677248;  // conv stat partials (64 x 576 = 36864)
  const size_t F_TAUP = 10714112;   // tau partials (1024 x 144 = 147456)
  float* sums = ws + F_STATS;
  float* sums2 = ws + F_STATS + 256;
  float* cpart = ws + F_CPART;
  float* taupart = ws + F_TAUP;
  float* lp = ws + F_LP;
  __bf16* wbase = (__bf16*)(ws + F_WB);
  __bf16* wb3 = (__bf16*)(ws + F_WB3);
  const int W_KV = 0;        // k(16384) | v(16384)
  const int W_R = 32768;     // 16384
  const int W_SN1 = 49152;   // 16384
  const int W_SN2 = 65536;   // 16384
  const int W_LBLD = 81920;  // lb(8192) | ld(8192)
  const int W_PS = 98304;    // 4096
  const int W_PQK = 102400;  // pq(16384) | k(16384) | v(16384)
  const int W_FC1 = 151552;  // 65536
  const int W_FC2 = 217088;  // 65536
  const int W3_OFF[4] = {0, 36864, 82944, 138240};

  dim3 blk(256);
  __bf16* xrope_t = (__bf16*)(ws + F_XR);
  __bf16* x_t = (__bf16*)(ws + F_XT);

  // --- prep: weight cvt + conv pack + x stats + x dual-transpose, ONE launch ---
  Prep pp;
  pp.wsrc[0] = k_w;    pp.wlen[0] = 16384; pp.woff[0] = W_KV;
  pp.wsrc[1] = v_w;    pp.wlen[1] = 16384; pp.woff[1] = W_KV + 16384;
  pp.wsrc[2] = r_w;    pp.wlen[2] = 16384; pp.woff[2] = W_R;
  pp.wsrc[3] = sn1_w;  pp.wlen[3] = 16384; pp.woff[3] = W_SN1;
  pp.wsrc[4] = sn2_w;  pp.wlen[4] = 16384; pp.woff[4] = W_SN2;
  pp.wsrc[5] = lb_w;   pp.wlen[5] = 8192;  pp.woff[5] = W_LBLD;
  pp.wsrc[6] = ld_w;   pp.wlen[6] = 8192;  pp.woff[6] = W_LBLD + 8192;
  pp.wsrc[7] = ps_w;   pp.wlen[7] = 4096;  pp.woff[7] = W_PS;
  pp.wsrc[8] = pq_w;   pp.wlen[8] = 16384; pp.woff[8] = W_PQK;
  pp.wsrc[9] = k_w;    pp.wlen[9] = 16384; pp.woff[9] = W_PQK + 16384;
  pp.wsrc[10] = v_w;   pp.wlen[10] = 16384; pp.woff[10] = W_PQK + 32768;
  pp.wsrc[11] = fc1_w; pp.wlen[11] = 65536; pp.woff[11] = W_FC1;
  pp.wsrc[12] = fc2_w; pp.wlen[12] = 65536; pp.woff[12] = W_FC2;
  for (int i = 0; i < 4; ++i) {
    pp.psrc[i] = db_w[i];
    pp.pcin[i] = 128 + 32 * i;
    pp.poff[i] = W3_OFF[i];
  }
  pp.x = x;
  pp.sums = sums;
  pp.sums2 = sums2;
  pp.x_t = x_t;
  pp.xrope_t = xrope_t;
  prep_kernel<<<dim3(256, 23), blk, 0, stream>>>(pp, wbase, wb3);

  // --- recurrent path: ONE fused k|v|r GEMM + rwkv epilogue ---
  kvr_kernel<<<dim3(144, 4), blk, 0, stream>>>(
      xrope_t, x_t, wbase + W_KV, wbase + W_KV + 16384, wbase + W_R,
      k_b, v_b, r_b, u, kden, knum, ws + F_REC);

  // --- dense block: incremental bnrelu, stats via per-block partials ---
  __bf16* ht = (__bf16*)(ws + F_V);
  __bf16* dense_t = (__bf16*)(ws + F_R);
  bnrelu_t_kernel<<<dim3(72, 4, 4), blk, 0, stream>>>(x, (size_t)128 * NSP, 0, sums, sums2,
                                                      nullptr, db_g[0], db_b[0], ht);
  conv3x3_mfma_kernel<128><<<dim3(144, 4), blk, 0, stream>>>(
      ht, wb3 + W3_OFF[0], db_cb[0], ws + F_FEATS, 128, dense_t, cpart);
  for (int i = 1; i < 4; ++i) {
    int cin = 128 + 32 * i;
    bnrelu_t_kernel<<<dim3(72, 1, 4), blk, 0, stream>>>(
        ws + F_FEATS + (size_t)(cin - 32) * NSP, (size_t)256 * NSP, cin - 32,
        nullptr, nullptr, cpart, db_g[i], db_b[i], ht);
    float* cp = (i < 3) ? cpart : nullptr;
    switch (cin) {
      case 160: conv3x3_mfma_kernel<160><<<dim3(144, 4), blk, 0, stream>>>(ht, wb3 + W3_OFF[i], db_cb[i], ws + F_FEATS, cin, dense_t, cp); break;
      case 192: conv3x3_mfma_kernel<192><<<dim3(144, 4), blk, 0, stream>>>(ht, wb3 + W3_OFF[i], db_cb[i], ws + F_FEATS, cin, dense_t, cp); break;
      default:  conv3x3_mfma_kernel<224><<<dim3(144, 4), blk, 0, stream>>>(ht, wb3 + W3_OFF[i], db_cb[i], ws + F_FEATS, cin, dense_t, cp); break;
    }
  }

  // --- spike path: sn1 reads split x_t|dense_t; tau partials; sf inline in lb/ld GEMM ---
  __bf16* z1_t = (__bf16*)(ws + F_XR);
  gemm_mfma_kernel<256, 1, 1, 1, 0, 1><<<dim3(144, 4, 1), dim3(128), 0, stream>>>(
      x_t, dense_t, wbase + W_SN1, sn1_b, sn1_b, nullptr, nullptr, nullptr,
      z1_t, z1_t, nullptr, 64, 64, 64, 1.f, 1.f, 1.f);
  gemm_mfma_kernel<64, 2, 3, 3, 0, 0><<<dim3(144, 4, 2), blk, 0, stream>>>(
      z1_t, nullptr, wbase + W_SN2, sn2_b, sn2_b, nullptr, nullptr, nullptr,
      taupart, taupart, nullptr, 256, 256, 256, 1.f, 1.f, 1.f);
  __bf16* Bft = (__bf16*)(ws + F_XT);  // overwrites x_t AFTER its last read? no: Bft aliases F_XT
  // NOTE: x_t (F_XT) is still needed by lbld_sf as raw df input — so Bft must NOT alias x_t.
  // Place Bft in F_AT1T region temporarily? att1_t used later. Use F_CT head instead (comb_t
  // written only after ps GEMM). Bft size = 147456 bf16 = 73728 f32 slots < F_CT region.
  Bft = (__bf16*)(ws + F_CT + 294912);  // upper half of F_CT region (x1_t uses lower later)
  __bf16* Dfb = (__bf16*)(ws + F_DFB);
  lbld_sf_kernel<<<dim3(144, 4), dim3(128), 0, stream>>>(
      x_t, dense_t, taupart, wbase + W_LBLD, lb_b, ld_b, Bft, Dfb);
  __bf16* Opart = (__bf16*)(ws + F_FEATS);  // feats f32 dead from here
  attn_part_kernel<32><<<dim3(36, 4, KS), blk, 0, stream>>>(Bft, Bft, Dfb, Opart, lp);
  __bf16* att1_t = (__bf16*)(ws + F_AT1T);
  combine32_kernel<<<dim3(72, 1, 4), blk, 0, stream>>>(Opart, lp, att1_t);
  __bf16* comb_t = (__bf16*)(ws + F_CT);
  gemm_mfma_kernel<32, 0, 1, 1, 0, 0><<<dim3(144, 4, 1), blk, 0, stream>>>(
      att1_t, nullptr, wbase + W_PS, ps_b, ps_b, nullptr, ws + F_REC, ws + F_REC,
      comb_t, comb_t, nullptr, 128, 128, 128, 1.f, 1.f, 1.f);

  // --- final attention: ONE 3-segment Q|K2|V2 GEMM, flash-LDS attn ---
  __bf16* Qt = (__bf16*)(ws + F_XR);
  __bf16* K2t = (__bf16*)(ws + F_XT);
  __bf16* V2b = (__bf16*)(ws + F_V);  // ht dead after conv3
  gemm_mfma_kernel<128, 0, 1, 1, 2, 0><<<dim3(144, 4, 3), blk, 0, stream>>>(
      comb_t, nullptr, wbase + W_PQK, pq_b, k_b, v_b, nullptr, nullptr,
      Qt, K2t, V2b, 128, 256, 384, 0.08838834764831845f, 1.f, 1.f);
  attn_part_kernel<128><<<dim3(36, 4, KS), blk, 0, stream>>>(Qt, K2t, V2b, Opart, lp);
  float* x1 = ws + F_R;  // dense_t dead after lbld_sf/sn1... (last read: lbld_sf)
  __bf16* x1_t = (__bf16*)(ws + F_CT);  // comb_t dead after QKV gemm (Bft upper half also dead)
  combine128_kernel<<<dim3(72, 4, 4), blk, 0, stream>>>(Opart, lp, x, x1, x1_t);

  // --- FFN tail ---
  __bf16* h_t = (__bf16*)(ws + F_FEATS);  // Op partials dead after combine
  gemm_mfma_kernel<128, 3, 1, 1, 0, 0><<<dim3(144, 4, 4), blk, 0, stream>>>(
      x1_t, nullptr, wbase + W_FC1, fc1_b, fc1_b, nullptr, nullptr, nullptr,
      h_t, h_t, nullptr, 512, 512, 512, 1.f, 1.f, 1.f);
  gemm_mfma_kernel<512, 0, 0, 0, 0, 0><<<dim3(144, 4, 1), blk, 0, stream>>>(
      h_t, nullptr, wbase + W_FC2, fc2_b, fc2_b, nullptr, x1, x1,
      outp, outp, nullptr, 128, 128, 128, 1.f, 1.f, 1.f);
}